// Round 4
// baseline (234.982 us; speedup 1.0000x reference)
//
#include <hip/hip_runtime.h>

typedef unsigned short u16;
typedef unsigned int u32;
typedef __attribute__((ext_vector_type(8))) short s16x8;
typedef __attribute__((ext_vector_type(4))) float f32x4;

#define DEV __device__ __forceinline__
#define MFMA16(a,b,c) __builtin_amdgcn_mfma_f32_16x16x32_bf16(a,b,c,0,0,0)

DEV float bf2f(u16 x){ u32 u=((u32)x)<<16; float f; __builtin_memcpy(&f,&u,4); return f; }
DEV u16 f2bf(float f){ u32 u; __builtin_memcpy(&u,&f,4); u32 r=u+0x7FFFu+((u>>16)&1u); return (u16)(r>>16); }
DEV uint4 pack8(const float* f){
  uint4 v;
  v.x=(u32)f2bf(f[0])|((u32)f2bf(f[1])<<16);
  v.y=(u32)f2bf(f[2])|((u32)f2bf(f[3])<<16);
  v.z=(u32)f2bf(f[4])|((u32)f2bf(f[5])<<16);
  v.w=(u32)f2bf(f[6])|((u32)f2bf(f[7])<<16);
  return v;
}
DEV float sigm(float x){ return 1.0f/(1.0f+__expf(-x)); }

// ---------------------------------------------------------------------------
// transpose tile helper: dst[n][k] = bf16(src[k][n]), 64x64 tile, 256 thr
// ---------------------------------------------------------------------------
DEV void trans_tile(const float* src, u16* dst, int K, int Nn, int bx, int by, int tid)
{
  __shared__ float ld[64][65];
  int n0 = bx*64, k0 = by*64;
  #pragma unroll
  for (int rr=0; rr<4; rr++){
    int kk = rr*16 + (tid>>4);
    int nn = (tid&15)*4;
    float4 v = *(const float4*)(src + (size_t)(k0+kk)*Nn + n0 + nn);
    ld[kk][nn]=v.x; ld[kk][nn+1]=v.y; ld[kk][nn+2]=v.z; ld[kk][nn+3]=v.w;
  }
  __syncthreads();
  int nn2 = tid>>2, kb = (tid&3)*16;
  float o[16];
  #pragma unroll
  for (int j=0;j<16;j++) o[j] = ld[kb+j][nn2];
  u16* dp = dst + (size_t)(n0+nn2)*K + k0 + kb;
  *(uint4*)dp     = pack8(&o[0]);
  *(uint4*)(dp+8) = pack8(&o[8]);
}

// merged big-weight transpose: blocks [0,128) Wkv, [128,192) Wq, [192,256) Wo
__global__ __launch_bounds__(256) void k_transAll(const float* __restrict__ Wkv,
    const float* __restrict__ Wq, const float* __restrict__ Wo,
    u16* __restrict__ Wkvt, u16* __restrict__ Wqt, u16* __restrict__ Wot)
{
  int blk = blockIdx.x, tid = threadIdx.x;
  if (blk < 128)      trans_tile(Wkv, Wkvt, 512, 1024, blk&15, blk>>4, tid);
  else if (blk < 192){ int l = blk-128; trans_tile(Wq, Wqt, 512, 512, l&7, l>>3, tid); }
  else                { int l = blk-192; trans_tile(Wo, Wot, 512, 512, l&7, l>>3, tid); }
}

// merged small prep: blocks 0-3 W1 trans, 4-7 W2 trans, 8-15 W2 conv
__global__ __launch_bounds__(256) void k_prepSmall(const float* __restrict__ MW1,
    const float* __restrict__ MW2, u16* __restrict__ W1t, u16* __restrict__ W2t,
    u16* __restrict__ W2s)
{
  int blk = blockIdx.x, tid = threadIdx.x;
  if (blk < 4)       trans_tile(MW1, W1t, 128, 128, blk&1, blk>>1, tid);
  else if (blk < 8)  { int l = blk-4; trans_tile(MW2, W2t, 128, 128, l&1, l>>1, tid); }
  else {
    int e = ((blk-8)*256 + tid)*8;
    float f[8];
    *(float4*)&f[0] = *(const float4*)(MW2+e);
    *(float4*)&f[4] = *(const float4*)(MW2+e+4);
    *(uint4*)(W2s+e) = pack8(f);
  }
}

// ---------------------------------------------------------------------------
// K1: per-token rmsnorm -> s, r (bf16), lr, gate. one wave per token.
// ---------------------------------------------------------------------------
__global__ __launch_bounds__(256) void k_token(const float* __restrict__ seq,
    const float* __restrict__ gs, const float* __restrict__ gr,
    const float* __restrict__ Wstep, const float* __restrict__ Wgate,
    u16* __restrict__ s, u16* __restrict__ r,
    float* __restrict__ lr, float* __restrict__ gate)
{
  int wv = threadIdx.x >> 6, lane = threadIdx.x & 63;
  int token = blockIdx.x*4 + wv;
  const float* row = seq + (size_t)token*512;
  float x[8];
  *(float4*)&x[0] = *(const float4*)(row + lane*8);
  *(float4*)&x[4] = *(const float4*)(row + lane*8 + 4);
  float ss = 0.f;
  #pragma unroll
  for (int j=0;j<8;j++) ss += x[j]*x[j];
  #pragma unroll
  for (int o=32;o>=1;o>>=1) ss += __shfl_xor(ss, o, 64);
  float inv = rsqrtf(ss*(1.0f/512.0f) + 1e-6f);
  float al[4] = {0,0,0,0}, ag[4] = {0,0,0,0};
  float sv8[8], rv8[8];
  #pragma unroll
  for (int j=0;j<8;j++){
    int d = lane*8 + j;
    float sn = x[j]*inv;
    float sv = sn*gs[d];
    float rv = sn*gr[d];
    sv8[j]=sv; rv8[j]=rv;
    float4 wst = *(const float4*)(Wstep + d*4);
    float4 wgt = *(const float4*)(Wgate + d*4);
    al[0]+=sv*wst.x; al[1]+=sv*wst.y; al[2]+=sv*wst.z; al[3]+=sv*wst.w;
    ag[0]+=rv*wgt.x; ag[1]+=rv*wgt.y; ag[2]+=rv*wgt.z; ag[3]+=rv*wgt.w;
  }
  *(uint4*)(s + (size_t)token*512 + lane*8) = pack8(sv8);
  *(uint4*)(r + (size_t)token*512 + lane*8) = pack8(rv8);
  #pragma unroll
  for (int o=32;o>=1;o>>=1){
    #pragma unroll
    for (int h=0;h<4;h++){ al[h] += __shfl_xor(al[h], o, 64); ag[h] += __shfl_xor(ag[h], o, 64); }
  }
  if (lane == 0){
    #pragma unroll
    for (int h=0;h<4;h++){
      lr[(size_t)token*4 + h]   = sigm(al[h]);
      gate[(size_t)token*4 + h] = sigm(ag[h]);
    }
  }
}

// ---------------------------------------------------------------------------
// K2: chunk means -> decay/mom gates.
// ---------------------------------------------------------------------------
__global__ __launch_bounds__(256) void k_chunk(const u16* __restrict__ s,
    const float* __restrict__ Wdec, const float* __restrict__ Wmom,
    float* __restrict__ momv, float* __restrict__ dgv)
{
  int b = blockIdx.x >> 6, ci = blockIdx.x & 63;
  int d = threadIdx.x;
  size_t base = ((size_t)b*4096 + (size_t)ci*64)*512;
  float a0 = 0.f, a1 = 0.f;
  #pragma unroll 4
  for (int t=0;t<64;t++){
    a0 += bf2f(s[base + (size_t)t*512 + d]);
    a1 += bf2f(s[base + (size_t)t*512 + d + 256]);
  }
  a0 *= (1.0f/64.0f); a1 *= (1.0f/64.0f);
  __shared__ float red[8][256];
  #pragma unroll
  for (int h=0;h<4;h++){
    red[h][d]   = a0*Wdec[d*4+h] + a1*Wdec[(d+256)*4+h];
    red[4+h][d] = a0*Wmom[d*4+h] + a1*Wmom[(d+256)*4+h];
  }
  __syncthreads();
  if (d < 8){
    float sum = 0.f;
    #pragma unroll 8
    for (int k=0;k<256;k++) sum += red[d][k];
    int h = d & 3;
    if (d < 4) dgv[((size_t)(b*4+h))*64 + ci] = 1.0f - sigm(sum);
    else       momv[((size_t)(b*4+h))*64 + ci] = sigm(sum);
  }
}

// ---------------------------------------------------------------------------
// K3: MFMA GEMM (unchanged from r3). A[M][K] bf16, Bt[N][K] bf16, C[M][N].
// ---------------------------------------------------------------------------
template<bool OUT_BF>
__global__ __launch_bounds__(256) void k_gemm(const u16* __restrict__ A,
    const u16* __restrict__ Bt, void* __restrict__ Cv, int K, int ldc)
{
  __shared__ u16 sA[128*72];
  __shared__ u16 sB[128*72];
  const int tid = threadIdx.x;
  const int wv = tid>>6, lane = tid&63, lrow = lane&15, lk = lane>>4;
  const int wm = (wv>>1)*64, wn = (wv&1)*64;
  const int rowbase = blockIdx.y*128, colbase = blockIdx.x*128;
  f32x4 acc[4][4] = {};
  for (int kc = 0; kc < K; kc += 64){
    __syncthreads();
    #pragma unroll
    for (int rep=0;rep<4;rep++){
      int lin = rep*2048 + tid*8;
      int rr = lin>>6, kk = lin&63;
      *(uint4*)&sA[rr*72+kk] = *(const uint4*)(A + (size_t)(rowbase+rr)*K + kc + kk);
      *(uint4*)&sB[rr*72+kk] = *(const uint4*)(Bt + (size_t)(colbase+rr)*K + kc + kk);
    }
    __syncthreads();
    #pragma unroll
    for (int k0=0;k0<2;k0++){
      s16x8 a[4], b[4];
      #pragma unroll
      for (int m=0;m<4;m++) a[m] = *(const s16x8*)&sA[(wm+m*16+lrow)*72 + k0*32 + lk*8];
      #pragma unroll
      for (int n=0;n<4;n++) b[n] = *(const s16x8*)&sB[(wn+n*16+lrow)*72 + k0*32 + lk*8];
      #pragma unroll
      for (int m=0;m<4;m++)
        #pragma unroll
        for (int n=0;n<4;n++)
          acc[m][n] = MFMA16(a[m], b[n], acc[m][n]);
    }
  }
  #pragma unroll
  for (int m=0;m<4;m++)
    #pragma unroll
    for (int n=0;n<4;n++)
      #pragma unroll
      for (int r=0;r<4;r++){
        int row = rowbase + wm + m*16 + lk*4 + r;
        int col = colbase + wn + n*16 + lrow;
        float v = acc[m][n][r];
        if (OUT_BF) ((u16*)Cv)[(size_t)row*ldc + col] = f2bf(v);
        else        ((float*)Cv)[(size_t)row*ldc + col] = v;
      }
}

// ---------------------------------------------------------------------------
// K4: per-chunk gradient. 512 threads / 8 waves per (bh,chunk). ~70KB LDS.
// Weights (W1t/W2t/W2s) read directly from global as MFMA fragments.
// Buffer reuse: bufR = kc -> As -> dP (row-major); bufAt = Ast -> dHt.
// Outputs s1t [d_h][d_in], s2t [d_out][d_h].
// ---------------------------------------------------------------------------
__global__ __launch_bounds__(512) void k_grad(const u16* __restrict__ kv,
    const float* __restrict__ lr, const u16* __restrict__ W1t,
    const u16* __restrict__ W2t, const u16* __restrict__ W2s,
    u16* __restrict__ s1, u16* __restrict__ s2)
{
  __shared__ u16 bufR[64*132];   // kc -> As -> dP (row-major, stride 132)
  __shared__ u16 bufKt[128*68];  // kct [d_in][i]
  __shared__ u16 bufAt[128*68];  // Ast [d_h][i] -> dHt [d_h][i]
  __shared__ u16 bufPt[128*68];  // dPt [d_out][i]
  __shared__ float lrs[64];

  const int blk = blockIdx.x;
  const int bhi = blk >> 6, ci = blk & 63;
  const int b = bhi >> 2, hd = bhi & 3;
  const int tid = threadIdx.x;
  const int wv = tid>>6, lane = tid&63, lrow = lane&15, lk = lane>>4;
  const int nb = wv*16;                 // 8 waves x 16 output cols
  const int colw = nb + lrow;           // this lane's output column
  const size_t rowbase = (size_t)b*4096 + (size_t)ci*64;

  // ---- stage0: kc row-major + transposed
  #pragma unroll
  for (int rep=0;rep<2;rep++){
    int lin = rep*4096 + tid*8;
    int i = lin >> 7, d = lin & 127;
    union { uint4 v; u16 h[8]; } u;
    u.v = *(const uint4*)(kv + (rowbase + i)*1024 + hd*128 + d);
    *(uint4*)&bufR[i*132 + d] = u.v;
    #pragma unroll
    for (int j=0;j<8;j++) bufKt[(d+j)*68 + i] = u.h[j];
  }
  if (tid < 64) lrs[tid] = lr[(rowbase + tid)*4 + hd] * (2.0f/128.0f);
  __syncthreads();

  float spv[4][4];

  // ---- mm1: H = kc @ W1 ; A = silu(H)
  {
    s16x8 wf[4];
    #pragma unroll
    for (int k0=0;k0<4;k0++) wf[k0] = *(const s16x8*)(W1t + colw*128 + k0*32 + lk*8);
    f32x4 acc[4] = {};
    #pragma unroll
    for (int k0=0;k0<4;k0++){
      #pragma unroll
      for (int m=0;m<4;m++){
        s16x8 a = *(const s16x8*)&bufR[(m*16+lrow)*132 + k0*32 + lk*8];
        acc[m] = MFMA16(a, wf[k0], acc[m]);
      }
    }
    __syncthreads();   // all waves done reading kc
    #pragma unroll
    for (int m=0;m<4;m++){
      int row0 = m*16 + lk*4;
      u16 av4[4];
      #pragma unroll
      for (int r=0;r<4;r++){
        float h = acc[m][r];
        float sg = sigm(h);
        av4[r] = f2bf(h*sg);
        spv[m][r] = sg*(1.0f + h*(1.0f - sg));
        bufR[(row0+r)*132 + colw] = av4[r];
      }
      *(uint2*)&bufAt[colw*68 + row0] = make_uint2(
        (u32)av4[0] | ((u32)av4[1]<<16), (u32)av4[2] | ((u32)av4[3]<<16));
    }
  }
  __syncthreads();

  // ---- mm2: P = A @ W2 ; dP = lr*(P - v)
  {
    s16x8 wf[4];
    #pragma unroll
    for (int k0=0;k0<4;k0++) wf[k0] = *(const s16x8*)(W2t + colw*128 + k0*32 + lk*8);
    f32x4 acc[4] = {};
    #pragma unroll
    for (int k0=0;k0<4;k0++){
      #pragma unroll
      for (int m=0;m<4;m++){
        s16x8 a = *(const s16x8*)&bufR[(m*16+lrow)*132 + k0*32 + lk*8];
        acc[m] = MFMA16(a, wf[k0], acc[m]);
      }
    }
    __syncthreads();   // all waves done reading As
    #pragma unroll
    for (int m=0;m<4;m++){
      int row0 = m*16 + lk*4;
      u16 dp4[4];
      #pragma unroll
      for (int r=0;r<4;r++){
        int row = row0 + r;
        float vv = bf2f(kv[(rowbase+row)*1024 + 512 + hd*128 + colw]);
        float dp = lrs[row]*(acc[m][r] - vv);
        dp4[r] = f2bf(dp);
        bufR[row*132 + colw] = dp4[r];
      }
      *(uint2*)&bufPt[colw*68 + row0] = make_uint2(
        (u32)dp4[0] | ((u32)dp4[1]<<16), (u32)dp4[2] | ((u32)dp4[3]<<16));
    }
  }
  __syncthreads();

  const size_t outbase = (size_t)blk * 16384;

  // ---- mm3: dA = dP @ W2^T (into regs)
  f32x4 da[4] = {};
  {
    s16x8 wf[4];
    #pragma unroll
    for (int k0=0;k0<4;k0++) wf[k0] = *(const s16x8*)(W2s + colw*128 + k0*32 + lk*8);
    #pragma unroll
    for (int k0=0;k0<4;k0++){
      #pragma unroll
      for (int m=0;m<4;m++){
        s16x8 a = *(const s16x8*)&bufR[(m*16+lrow)*132 + k0*32 + lk*8];
        da[m] = MFMA16(a, wf[k0], da[m]);
      }
    }
  }
  // ---- mm4: s2t[d_out][d_h] = -(dPt x Ast)
  {
    f32x4 acc[8] = {};
    #pragma unroll
    for (int k0=0;k0<2;k0++){
      s16x8 bf = *(const s16x8*)&bufAt[colw*68 + k0*32 + lk*8];
      #pragma unroll
      for (int m=0;m<8;m++){
        s16x8 a = *(const s16x8*)&bufPt[(m*16+lrow)*68 + k0*32 + lk*8];
        acc[m] = MFMA16(a, bf, acc[m]);
      }
    }
    #pragma unroll
    for (int m=0;m<8;m++)
      #pragma unroll
      for (int r=0;r<4;r++)
        s2[outbase + (size_t)(m*16 + lk*4 + r)*128 + colw] = f2bf(-acc[m][r]);
  }
  __syncthreads();   // all waves done reading bufAt (mm4)
  // write dHt = spv * dA into bufAt
  #pragma unroll
  for (int m=0;m<4;m++){
    int row0 = m*16 + lk*4;
    u16 dh4[4];
    #pragma unroll
    for (int r=0;r<4;r++) dh4[r] = f2bf(spv[m][r]*da[m][r]);
    *(uint2*)&bufAt[colw*68 + row0] = make_uint2(
      (u32)dh4[0] | ((u32)dh4[1]<<16), (u32)dh4[2] | ((u32)dh4[3]<<16));
  }
  __syncthreads();

  // ---- mm5: s1t[d_h][d_in] = -(dHt x kct)
  {
    f32x4 acc[8] = {};
    #pragma unroll
    for (int k0=0;k0<2;k0++){
      s16x8 bf = *(const s16x8*)&bufKt[colw*68 + k0*32 + lk*8];
      #pragma unroll
      for (int m=0;m<8;m++){
        s16x8 a = *(const s16x8*)&bufAt[(m*16+lrow)*68 + k0*32 + lk*8];
        acc[m] = MFMA16(a, bf, acc[m]);
      }
    }
    #pragma unroll
    for (int m=0;m<8;m++)
      #pragma unroll
      for (int r=0;r<4;r++)
        s1[outbase + (size_t)(m*16 + lk*4 + r)*128 + colw] = f2bf(-acc[m][r]);
  }
}

// ---------------------------------------------------------------------------
// K5: fused momentum + decay scans (transposed layout; elementwise, in-place).
// ---------------------------------------------------------------------------
__global__ __launch_bounds__(256) void k_scan(const float* __restrict__ momv,
    const float* __restrict__ dgv, const float* __restrict__ MW1,
    const float* __restrict__ MW2, u16* __restrict__ s1w, u16* __restrict__ s2w)
{
  int bhi = blockIdx.x >> 6, eb = blockIdx.x & 63;
  int e = eb*256 + threadIdx.x;
  float u1 = MW1[(e&127)*128 + (e>>7)];
  float u2 = MW2[(e&127)*128 + (e>>7)];
  float m1 = 0.f, m2 = 0.f;
  size_t base = (size_t)bhi*64*16384 + e;
  #pragma unroll 1
  for (int t=0; t<64; t++){
    float g  = momv[bhi*64 + t];
    float dg = dgv[bhi*64 + t];
    size_t idx = base + (size_t)t*16384;
    float g1v = bf2f(s1w[idx]);
    float g2v = bf2f(s2w[idx]);
    s1w[idx] = f2bf(u1);
    s2w[idx] = f2bf(u2);
    m1 = g*m1 + g1v;
    m2 = g*m2 + g2v;
    u1 = dg*u1 + m1;
    u2 = dg*u2 + m2;
  }
}

// ---------------------------------------------------------------------------
// K6: retrieval. 512 threads / 8 waves. q + w1c/w2c fragments direct from
// global; only As + rsum in LDS (~19KB). rmsnorm*(gamma+1)*gate epilogue.
// ---------------------------------------------------------------------------
__global__ __launch_bounds__(512) void k_retr(const u16* __restrict__ qin,
    const u16* __restrict__ w1c, const u16* __restrict__ w2c,
    const float* __restrict__ gate, const float* __restrict__ gamma,
    u16* __restrict__ outp)
{
  __shared__ u16 bufA[64*132];
  __shared__ float rsum[8][64];
  const int blk = blockIdx.x;
  const int bhi = blk >> 6, ci = blk & 63;
  const int b = bhi >> 2, hd = bhi & 3;
  const int tid = threadIdx.x;
  const int wv = tid>>6, lane = tid&63, lrow = lane&15, lk = lane>>4;
  const int nb = wv*16;
  const int colw = nb + lrow;
  const size_t rowbase = (size_t)b*4096 + (size_t)ci*64;
  const u16* w1 = w1c + (size_t)blk*16384;
  const u16* w2 = w2c + (size_t)blk*16384;

  // mm1: Hq = q @ w1 ; A = silu(Hq)
  {
    s16x8 wf[4];
    #pragma unroll
    for (int k0=0;k0<4;k0++) wf[k0] = *(const s16x8*)(w1 + colw*128 + k0*32 + lk*8);
    f32x4 acc[4] = {};
    #pragma unroll
    for (int k0=0;k0<4;k0++){
      #pragma unroll
      for (int m=0;m<4;m++){
        s16x8 a = *(const s16x8*)(qin + (rowbase + m*16+lrow)*512 + hd*128 + k0*32 + lk*8);
        acc[m] = MFMA16(a, wf[k0], acc[m]);
      }
    }
    #pragma unroll
    for (int m=0;m<4;m++){
      #pragma unroll
      for (int r=0;r<4;r++){
        float h = acc[m][r];
        bufA[(m*16+lk*4+r)*132 + colw] = f2bf(h*sigm(h));
      }
    }
  }
  __syncthreads();

  // mm2: P = A @ w2
  f32x4 acc[4] = {};
  {
    s16x8 wf[4];
    #pragma unroll
    for (int k0=0;k0<4;k0++) wf[k0] = *(const s16x8*)(w2 + colw*128 + k0*32 + lk*8);
    #pragma unroll
    for (int k0=0;k0<4;k0++){
      #pragma unroll
      for (int m=0;m<4;m++){
        s16x8 a = *(const s16x8*)&bufA[(m*16+lrow)*132 + k0*32 + lk*8];
        acc[m] = MFMA16(a, wf[k0], acc[m]);
      }
    }
  }
  // row sums of squares: in-wave over lrow, cross-wave via LDS
  #pragma unroll
  for (int m=0;m<4;m++){
    #pragma unroll
    for (int r=0;r<4;r++){
      float p = acc[m][r]*acc[m][r];
      p += __shfl_xor(p, 1, 64);
      p += __shfl_xor(p, 2, 64);
      p += __shfl_xor(p, 4, 64);
      p += __shfl_xor(p, 8, 64);
      if (lrow == 0) rsum[wv][m*16 + lk*4 + r] = p;
    }
  }
  __syncthreads();
  float gm = gamma[hd*128 + colw] + 1.0f;
  #pragma unroll
  for (int m=0;m<4;m++){
    #pragma unroll
    for (int r=0;r<4;r++){
      int row = m*16 + lk*4 + r;
      float sum = rsum[0][row]+rsum[1][row]+rsum[2][row]+rsum[3][row]
                + rsum[4][row]+rsum[5][row]+rsum[6][row]+rsum[7][row];
      float inv = rsqrtf(sum*(1.0f/128.0f) + 1e-6f);
      float gt = gate[(rowbase+row)*4 + hd];
      outp[(rowbase+row)*512 + hd*128 + colw] = f2bf(acc[m][r]*inv*gm*gt);
    }
  }
}

// ---------------------------------------------------------------------------
extern "C" void kernel_launch(void* const* d_in, const int* in_sizes, int n_in,
                              void* d_out, int out_size, void* d_ws, size_t ws_size,
                              hipStream_t stream)
{
  const float* seq    = (const float*)d_in[0];
  const float* gstore = (const float*)d_in[1];
  const float* gret   = (const float*)d_in[2];
  const float* W_q    = (const float*)d_in[3];
  const float* W_kv   = (const float*)d_in[4];
  const float* W_step = (const float*)d_in[5];
  const float* W_mom  = (const float*)d_in[6];
  const float* W_dec  = (const float*)d_in[7];
  const float* W_gate = (const float*)d_in[8];
  const float* gamma  = (const float*)d_in[9];
  const float* W_o    = (const float*)d_in[10];
  const float* MW1    = (const float*)d_in[11];
  const float* MW2    = (const float*)d_in[12];
  float* out = (float*)d_out;

  const size_t NS = (size_t)16384*512;
  const size_t NG = (size_t)16*64*16384;
  size_t need = (5*NS + 2*NG + 524288 + 262144 + 262144 + 3*16384)*2
              + (2*65536 + 2048)*4;
  if (ws_size < need) return;

  char* ws = (char*)d_ws;
  u16* s_bf = (u16*)ws; ws += NS*2;        // s; reused as outp
  u16* r_bf = (u16*)ws; ws += NS*2;
  u16* kv_bf= (u16*)ws; ws += 2*NS*2;
  u16* q_bf = (u16*)ws; ws += NS*2;
  u16* s1   = (u16*)ws; ws += NG*2;        // -> w1c after k_scan
  u16* s2   = (u16*)ws; ws += NG*2;        // -> w2c
  u16* Wkvt = (u16*)ws; ws += (size_t)524288*2;
  u16* Wqt  = (u16*)ws; ws += (size_t)262144*2;
  u16* Wot  = (u16*)ws; ws += (size_t)262144*2;
  u16* W1tb = (u16*)ws; ws += (size_t)16384*2;
  u16* W2tb = (u16*)ws; ws += (size_t)16384*2;
  u16* W2sb = (u16*)ws; ws += (size_t)16384*2;
  float* lr   = (float*)ws; ws += (size_t)65536*4;
  float* gatep= (float*)ws; ws += (size_t)65536*4;
  float* momv = (float*)ws; ws += 1024*4;
  float* dgv  = (float*)ws; ws += 1024*4;
  u16* outp = s_bf;

  k_transAll<<<256, 256, 0, stream>>>(W_kv, W_q, W_o, Wkvt, Wqt, Wot);
  k_prepSmall<<<16, 256, 0, stream>>>(MW1, MW2, W1tb, W2tb, W2sb);

  k_token<<<4096, 256, 0, stream>>>(seq, gstore, gret, W_step, W_gate, s_bf, r_bf, lr, gatep);
  k_chunk<<<256, 256, 0, stream>>>(s_bf, W_dec, W_mom, momv, dgv);
  k_gemm<true><<<dim3(8,128), 256, 0, stream>>>(s_bf, Wkvt, kv_bf, 512, 1024);
  k_gemm<true><<<dim3(4,128), 256, 0, stream>>>(r_bf, Wqt, q_bf, 512, 512);
  k_grad<<<1024, 512, 0, stream>>>(kv_bf, lr, W1tb, W2tb, W2sb, s1, s2);
  k_scan<<<1024, 256, 0, stream>>>(momv, dgv, MW1, MW2, s1, s2);
  k_retr<<<1024, 512, 0, stream>>>(q_bf, s1, s2, gatep, gamma, outp);
  k_gemm<false><<<dim3(4,128), 256, 0, stream>>>(outp, Wot, out, 512, 512);
}

// Round 5
// 216.023 us; speedup vs baseline: 1.0878x; 1.0878x over previous
//
#include <hip/hip_runtime.h>

typedef unsigned short u16;
typedef unsigned int u32;
typedef __attribute__((ext_vector_type(8))) short s16x8;
typedef __attribute__((ext_vector_type(4))) float f32x4;

#define DEV __device__ __forceinline__
#define MFMA16(a,b,c) __builtin_amdgcn_mfma_f32_16x16x32_bf16(a,b,c,0,0,0)

DEV float bf2f(u16 x){ u32 u=((u32)x)<<16; float f; __builtin_memcpy(&f,&u,4); return f; }
DEV u16 f2bf(float f){ u32 u; __builtin_memcpy(&u,&f,4); u32 r=u+0x7FFFu+((u>>16)&1u); return (u16)(r>>16); }
DEV uint4 pack8(const float* f){
  uint4 v;
  v.x=(u32)f2bf(f[0])|((u32)f2bf(f[1])<<16);
  v.y=(u32)f2bf(f[2])|((u32)f2bf(f[3])<<16);
  v.z=(u32)f2bf(f[4])|((u32)f2bf(f[5])<<16);
  v.w=(u32)f2bf(f[6])|((u32)f2bf(f[7])<<16);
  return v;
}
DEV float sigm(float x){ return 1.0f/(1.0f+__expf(-x)); }

// ---------------------------------------------------------------------------
// transpose tile helper: dst[n][k] = bf16(src[k][n]), 64x64 tile, 256 thr
// ---------------------------------------------------------------------------
DEV void trans_tile(const float* src, u16* dst, int K, int Nn, int bx, int by, int tid)
{
  __shared__ float ld[64][65];
  int n0 = bx*64, k0 = by*64;
  #pragma unroll
  for (int rr=0; rr<4; rr++){
    int kk = rr*16 + (tid>>4);
    int nn = (tid&15)*4;
    float4 v = *(const float4*)(src + (size_t)(k0+kk)*Nn + n0 + nn);
    ld[kk][nn]=v.x; ld[kk][nn+1]=v.y; ld[kk][nn+2]=v.z; ld[kk][nn+3]=v.w;
  }
  __syncthreads();
  int nn2 = tid>>2, kb = (tid&3)*16;
  float o[16];
  #pragma unroll
  for (int j=0;j<16;j++) o[j] = ld[kb+j][nn2];
  u16* dp = dst + (size_t)(n0+nn2)*K + k0 + kb;
  *(uint4*)dp     = pack8(&o[0]);
  *(uint4*)(dp+8) = pack8(&o[8]);
}

// merged weight prep:
// blocks [0,128) Wkv trans, [128,192) Wq, [192,256) Wo, [256,260) W1t,
// [260,264) W2t, [264,272) W2 conv
__global__ __launch_bounds__(256) void k_prep(const float* __restrict__ Wkv,
    const float* __restrict__ Wq, const float* __restrict__ Wo,
    const float* __restrict__ MW1, const float* __restrict__ MW2,
    u16* __restrict__ Wkvt, u16* __restrict__ Wqt, u16* __restrict__ Wot,
    u16* __restrict__ W1t, u16* __restrict__ W2t, u16* __restrict__ W2s)
{
  int blk = blockIdx.x, tid = threadIdx.x;
  if (blk < 128)      trans_tile(Wkv, Wkvt, 512, 1024, blk&15, blk>>4, tid);
  else if (blk < 192){ int l = blk-128; trans_tile(Wq, Wqt, 512, 512, l&7, l>>3, tid); }
  else if (blk < 256){ int l = blk-192; trans_tile(Wo, Wot, 512, 512, l&7, l>>3, tid); }
  else if (blk < 260){ int l = blk-256; trans_tile(MW1, W1t, 128, 128, l&1, l>>1, tid); }
  else if (blk < 264){ int l = blk-260; trans_tile(MW2, W2t, 128, 128, l&1, l>>1, tid); }
  else {
    int e = ((blk-264)*256 + tid)*8;
    float f[8];
    *(float4*)&f[0] = *(const float4*)(MW2+e);
    *(float4*)&f[4] = *(const float4*)(MW2+e+4);
    *(uint4*)(W2s+e) = pack8(f);
  }
}

// ---------------------------------------------------------------------------
// K1: merged per-token rmsnorm (s, r, lr, gate) + chunk mean -> decay/mom.
// one block per (b, chunk): 512 thr / 8 waves, each wave 8 tokens.
// ---------------------------------------------------------------------------
__global__ __launch_bounds__(512) void k_tokchunk(const float* __restrict__ seq,
    const float* __restrict__ gs, const float* __restrict__ gr,
    const float* __restrict__ Wstep, const float* __restrict__ Wgate,
    const float* __restrict__ Wdec, const float* __restrict__ Wmom,
    u16* __restrict__ s, u16* __restrict__ r,
    float* __restrict__ lr, float* __restrict__ gate,
    float* __restrict__ momv, float* __restrict__ dgv)
{
  __shared__ float pchunk[8][512];
  __shared__ float red[8][512];
  const int blk = blockIdx.x;
  const int b = blk >> 6, ci = blk & 63;
  const int tid = threadIdx.x;
  const int wv = tid >> 6, lane = tid & 63;
  const size_t rowbase = (size_t)b*4096 + (size_t)ci*64;

  float psum[8] = {0,0,0,0,0,0,0,0};
  #pragma unroll 1
  for (int tt=0; tt<8; tt++){
    int t = wv*8 + tt;
    const float* row = seq + (rowbase + t)*512;
    float x[8];
    *(float4*)&x[0] = *(const float4*)(row + lane*8);
    *(float4*)&x[4] = *(const float4*)(row + lane*8 + 4);
    float ss = 0.f;
    #pragma unroll
    for (int j=0;j<8;j++) ss += x[j]*x[j];
    #pragma unroll
    for (int o=32;o>=1;o>>=1) ss += __shfl_xor(ss, o, 64);
    float inv = rsqrtf(ss*(1.0f/512.0f) + 1e-6f);
    float al[4] = {0,0,0,0}, ag[4] = {0,0,0,0};
    float sv8[8], rv8[8];
    #pragma unroll
    for (int j=0;j<8;j++){
      int d = lane*8 + j;
      float sn = x[j]*inv;
      float sv = sn*gs[d];
      float rv = sn*gr[d];
      sv8[j]=sv; rv8[j]=rv;
      psum[j] += sv;
      float4 wst = *(const float4*)(Wstep + d*4);
      float4 wgt = *(const float4*)(Wgate + d*4);
      al[0]+=sv*wst.x; al[1]+=sv*wst.y; al[2]+=sv*wst.z; al[3]+=sv*wst.w;
      ag[0]+=rv*wgt.x; ag[1]+=rv*wgt.y; ag[2]+=rv*wgt.z; ag[3]+=rv*wgt.w;
    }
    *(uint4*)(s + (rowbase+t)*512 + lane*8) = pack8(sv8);
    *(uint4*)(r + (rowbase+t)*512 + lane*8) = pack8(rv8);
    #pragma unroll
    for (int o=32;o>=1;o>>=1){
      #pragma unroll
      for (int h=0;h<4;h++){ al[h] += __shfl_xor(al[h], o, 64); ag[h] += __shfl_xor(ag[h], o, 64); }
    }
    if (lane == 0){
      #pragma unroll
      for (int h=0;h<4;h++){
        lr[(rowbase+t)*4 + h]   = sigm(al[h]);
        gate[(rowbase+t)*4 + h] = sigm(ag[h]);
      }
    }
  }
  #pragma unroll
  for (int j=0;j<8;j++) pchunk[wv][lane*8+j] = psum[j];
  __syncthreads();

  // thread tid owns dim d = tid
  {
    int d = tid;
    float mean = 0.f;
    #pragma unroll
    for (int w=0;w<8;w++) mean += pchunk[w][d];
    mean *= (1.0f/64.0f);
    #pragma unroll
    for (int h=0;h<4;h++){
      red[h][d]   = mean*Wdec[d*4+h];
      red[4+h][d] = mean*Wmom[d*4+h];
    }
  }
  __syncthreads();
  // wave wv reduces red[wv][*]
  {
    float sum = 0.f;
    #pragma unroll
    for (int j=0;j<8;j++) sum += red[wv][lane*8+j];
    #pragma unroll
    for (int o=32;o>=1;o>>=1) sum += __shfl_xor(sum, o, 64);
    if (lane == 0){
      if (wv < 4) dgv[((size_t)(b*4+wv))*64 + ci]     = 1.0f - sigm(sum);
      else        momv[((size_t)(b*4+(wv-4)))*64 + ci] = sigm(sum);
    }
  }
}

// ---------------------------------------------------------------------------
// K3: MFMA GEMM, m97 structure: global_load_lds width-16 staging, linear LDS,
// 128x128 tile, BK=64, 4 waves (2x2), each 64x64.
// A[M][K] bf16, Bt[N][K] bf16, C[M][N].
// ---------------------------------------------------------------------------
template<bool OUT_BF>
__global__ __launch_bounds__(256) void k_gemm(const u16* __restrict__ A,
    const u16* __restrict__ Bt, void* __restrict__ Cv, int K, int ldc)
{
  __shared__ u16 sA[128*64];
  __shared__ u16 sB[128*64];
  const int tid = threadIdx.x;
  const int wv = tid>>6, lane = tid&63, lrow = lane&15, lk = lane>>4;
  const int wm = (wv>>1)*64, wn = (wv&1)*64;
  const int rowbase = blockIdx.y*128, colbase = blockIdx.x*128;
  const int srow = lane>>3;        // 0..7
  const int scol = (lane&7)*8;     // u16 units, 16B aligned
  f32x4 acc[4][4] = {};
  for (int kc = 0; kc < K; kc += 64){
    __syncthreads();
    #pragma unroll
    for (int it=0; it<4; ++it){
      int seg = it*4 + wv;         // 0..15, wave-contiguous 1KB segments
      int row = seg*8 + srow;
      __builtin_amdgcn_global_load_lds(
        (const __attribute__((address_space(1))) void*)(A + (size_t)(rowbase+row)*K + kc + scol),
        (__attribute__((address_space(3))) void*)&sA[seg*512 + lane*8], 16, 0, 0);
      __builtin_amdgcn_global_load_lds(
        (const __attribute__((address_space(1))) void*)(Bt + (size_t)(colbase+row)*K + kc + scol),
        (__attribute__((address_space(3))) void*)&sB[seg*512 + lane*8], 16, 0, 0);
    }
    __syncthreads();
    #pragma unroll
    for (int k0=0;k0<2;k0++){
      s16x8 a[4], b[4];
      #pragma unroll
      for (int m=0;m<4;m++) a[m] = *(const s16x8*)&sA[(wm+m*16+lrow)*64 + k0*32 + lk*8];
      #pragma unroll
      for (int n=0;n<4;n++) b[n] = *(const s16x8*)&sB[(wn+n*16+lrow)*64 + k0*32 + lk*8];
      #pragma unroll
      for (int m=0;m<4;m++)
        #pragma unroll
        for (int n=0;n<4;n++)
          acc[m][n] = MFMA16(a[m], b[n], acc[m][n]);
    }
  }
  #pragma unroll
  for (int m=0;m<4;m++)
    #pragma unroll
    for (int n=0;n<4;n++)
      #pragma unroll
      for (int r=0;r<4;r++){
        int row = rowbase + wm + m*16 + lk*4 + r;
        int col = colbase + wn + n*16 + lrow;
        float v = acc[m][n][r];
        if (OUT_BF) ((u16*)Cv)[(size_t)row*ldc + col] = f2bf(v);
        else        ((float*)Cv)[(size_t)row*ldc + col] = v;
      }
}

// ---------------------------------------------------------------------------
// K4: per-chunk gradient (unchanged from r4). 512 thr / 8 waves per (bh,chunk).
// ---------------------------------------------------------------------------
__global__ __launch_bounds__(512) void k_grad(const u16* __restrict__ kv,
    const float* __restrict__ lr, const u16* __restrict__ W1t,
    const u16* __restrict__ W2t, const u16* __restrict__ W2s,
    u16* __restrict__ s1, u16* __restrict__ s2)
{
  __shared__ u16 bufR[64*132];   // kc -> As -> dP (row-major, stride 132)
  __shared__ u16 bufKt[128*68];  // kct [d_in][i]
  __shared__ u16 bufAt[128*68];  // Ast [d_h][i] -> dHt [d_h][i]
  __shared__ u16 bufPt[128*68];  // dPt [d_out][i]
  __shared__ float lrs[64];

  const int blk = blockIdx.x;
  const int bhi = blk >> 6, ci = blk & 63;
  const int b = bhi >> 2, hd = bhi & 3;
  const int tid = threadIdx.x;
  const int wv = tid>>6, lane = tid&63, lrow = lane&15, lk = lane>>4;
  const int nb = wv*16;
  const int colw = nb + lrow;
  const size_t rowbase = (size_t)b*4096 + (size_t)ci*64;

  #pragma unroll
  for (int rep=0;rep<2;rep++){
    int lin = rep*4096 + tid*8;
    int i = lin >> 7, d = lin & 127;
    union { uint4 v; u16 h[8]; } u;
    u.v = *(const uint4*)(kv + (rowbase + i)*1024 + hd*128 + d);
    *(uint4*)&bufR[i*132 + d] = u.v;
    #pragma unroll
    for (int j=0;j<8;j++) bufKt[(d+j)*68 + i] = u.h[j];
  }
  if (tid < 64) lrs[tid] = lr[(rowbase + tid)*4 + hd] * (2.0f/128.0f);
  __syncthreads();

  float spv[4][4];

  // mm1: H = kc @ W1 ; A = silu(H)
  {
    s16x8 wf[4];
    #pragma unroll
    for (int k0=0;k0<4;k0++) wf[k0] = *(const s16x8*)(W1t + colw*128 + k0*32 + lk*8);
    f32x4 acc[4] = {};
    #pragma unroll
    for (int k0=0;k0<4;k0++){
      #pragma unroll
      for (int m=0;m<4;m++){
        s16x8 a = *(const s16x8*)&bufR[(m*16+lrow)*132 + k0*32 + lk*8];
        acc[m] = MFMA16(a, wf[k0], acc[m]);
      }
    }
    __syncthreads();
    #pragma unroll
    for (int m=0;m<4;m++){
      int row0 = m*16 + lk*4;
      u16 av4[4];
      #pragma unroll
      for (int r=0;r<4;r++){
        float h = acc[m][r];
        float sg = sigm(h);
        av4[r] = f2bf(h*sg);
        spv[m][r] = sg*(1.0f + h*(1.0f - sg));
        bufR[(row0+r)*132 + colw] = av4[r];
      }
      *(uint2*)&bufAt[colw*68 + row0] = make_uint2(
        (u32)av4[0] | ((u32)av4[1]<<16), (u32)av4[2] | ((u32)av4[3]<<16));
    }
  }
  __syncthreads();

  // mm2: P = A @ W2 ; dP = lr*(P - v)
  {
    s16x8 wf[4];
    #pragma unroll
    for (int k0=0;k0<4;k0++) wf[k0] = *(const s16x8*)(W2t + colw*128 + k0*32 + lk*8);
    f32x4 acc[4] = {};
    #pragma unroll
    for (int k0=0;k0<4;k0++){
      #pragma unroll
      for (int m=0;m<4;m++){
        s16x8 a = *(const s16x8*)&bufR[(m*16+lrow)*132 + k0*32 + lk*8];
        acc[m] = MFMA16(a, wf[k0], acc[m]);
      }
    }
    __syncthreads();
    #pragma unroll
    for (int m=0;m<4;m++){
      int row0 = m*16 + lk*4;
      u16 dp4[4];
      #pragma unroll
      for (int r=0;r<4;r++){
        int row = row0 + r;
        float vv = bf2f(kv[(rowbase+row)*1024 + 512 + hd*128 + colw]);
        float dp = lrs[row]*(acc[m][r] - vv);
        dp4[r] = f2bf(dp);
        bufR[row*132 + colw] = dp4[r];
      }
      *(uint2*)&bufPt[colw*68 + row0] = make_uint2(
        (u32)dp4[0] | ((u32)dp4[1]<<16), (u32)dp4[2] | ((u32)dp4[3]<<16));
    }
  }
  __syncthreads();

  const size_t outbase = (size_t)blk * 16384;

  // mm3: dA = dP @ W2^T (into regs)
  f32x4 da[4] = {};
  {
    s16x8 wf[4];
    #pragma unroll
    for (int k0=0;k0<4;k0++) wf[k0] = *(const s16x8*)(W2s + colw*128 + k0*32 + lk*8);
    #pragma unroll
    for (int k0=0;k0<4;k0++){
      #pragma unroll
      for (int m=0;m<4;m++){
        s16x8 a = *(const s16x8*)&bufR[(m*16+lrow)*132 + k0*32 + lk*8];
        da[m] = MFMA16(a, wf[k0], da[m]);
      }
    }
  }
  // mm4: s2t[d_out][d_h] = -(dPt x Ast)
  {
    f32x4 acc[8] = {};
    #pragma unroll
    for (int k0=0;k0<2;k0++){
      s16x8 bf = *(const s16x8*)&bufAt[colw*68 + k0*32 + lk*8];
      #pragma unroll
      for (int m=0;m<8;m++){
        s16x8 a = *(const s16x8*)&bufPt[(m*16+lrow)*68 + k0*32 + lk*8];
        acc[m] = MFMA16(a, bf, acc[m]);
      }
    }
    #pragma unroll
    for (int m=0;m<8;m++)
      #pragma unroll
      for (int r=0;r<4;r++)
        s2[outbase + (size_t)(m*16 + lk*4 + r)*128 + colw] = f2bf(-acc[m][r]);
  }
  __syncthreads();
  #pragma unroll
  for (int m=0;m<4;m++){
    int row0 = m*16 + lk*4;
    u16 dh4[4];
    #pragma unroll
    for (int r=0;r<4;r++) dh4[r] = f2bf(spv[m][r]*da[m][r]);
    *(uint2*)&bufAt[colw*68 + row0] = make_uint2(
      (u32)dh4[0] | ((u32)dh4[1]<<16), (u32)dh4[2] | ((u32)dh4[3]<<16));
  }
  __syncthreads();

  // mm5: s1t[d_h][d_in] = -(dHt x kct)
  {
    f32x4 acc[8] = {};
    #pragma unroll
    for (int k0=0;k0<2;k0++){
      s16x8 bf = *(const s16x8*)&bufKt[colw*68 + k0*32 + lk*8];
      #pragma unroll
      for (int m=0;m<8;m++){
        s16x8 a = *(const s16x8*)&bufAt[(m*16+lrow)*68 + k0*32 + lk*8];
        acc[m] = MFMA16(a, bf, acc[m]);
      }
    }
    #pragma unroll
    for (int m=0;m<8;m++)
      #pragma unroll
      for (int r=0;r<4;r++)
        s1[outbase + (size_t)(m*16 + lk*4 + r)*128 + colw] = f2bf(-acc[m][r]);
  }
}

// ---------------------------------------------------------------------------
// K5: fused momentum + decay scans (unchanged).
// ---------------------------------------------------------------------------
__global__ __launch_bounds__(256) void k_scan(const float* __restrict__ momv,
    const float* __restrict__ dgv, const float* __restrict__ MW1,
    const float* __restrict__ MW2, u16* __restrict__ s1w, u16* __restrict__ s2w)
{
  int bhi = blockIdx.x >> 6, eb = blockIdx.x & 63;
  int e = eb*256 + threadIdx.x;
  float u1 = MW1[(e&127)*128 + (e>>7)];
  float u2 = MW2[(e&127)*128 + (e>>7)];
  float m1 = 0.f, m2 = 0.f;
  size_t base = (size_t)bhi*64*16384 + e;
  #pragma unroll 1
  for (int t=0; t<64; t++){
    float g  = momv[bhi*64 + t];
    float dg = dgv[bhi*64 + t];
    size_t idx = base + (size_t)t*16384;
    float g1v = bf2f(s1w[idx]);
    float g2v = bf2f(s2w[idx]);
    s1w[idx] = f2bf(u1);
    s2w[idx] = f2bf(u2);
    m1 = g*m1 + g1v;
    m2 = g*m2 + g2v;
    u1 = dg*u1 + m1;
    u2 = dg*u2 + m2;
  }
}

// ---------------------------------------------------------------------------
// K6: retrieval (unchanged from r4).
// ---------------------------------------------------------------------------
__global__ __launch_bounds__(512) void k_retr(const u16* __restrict__ qin,
    const u16* __restrict__ w1c, const u16* __restrict__ w2c,
    const float* __restrict__ gate, const float* __restrict__ gamma,
    u16* __restrict__ outp)
{
  __shared__ u16 bufA[64*132];
  __shared__ float rsum[8][64];
  const int blk = blockIdx.x;
  const int bhi = blk >> 6, ci = blk & 63;
  const int b = bhi >> 2, hd = bhi & 3;
  const int tid = threadIdx.x;
  const int wv = tid>>6, lane = tid&63, lrow = lane&15, lk = lane>>4;
  const int nb = wv*16;
  const int colw = nb + lrow;
  const size_t rowbase = (size_t)b*4096 + (size_t)ci*64;
  const u16* w1 = w1c + (size_t)blk*16384;
  const u16* w2 = w2c + (size_t)blk*16384;

  {
    s16x8 wf[4];
    #pragma unroll
    for (int k0=0;k0<4;k0++) wf[k0] = *(const s16x8*)(w1 + colw*128 + k0*32 + lk*8);
    f32x4 acc[4] = {};
    #pragma unroll
    for (int k0=0;k0<4;k0++){
      #pragma unroll
      for (int m=0;m<4;m++){
        s16x8 a = *(const s16x8*)(qin + (rowbase + m*16+lrow)*512 + hd*128 + k0*32 + lk*8);
        acc[m] = MFMA16(a, wf[k0], acc[m]);
      }
    }
    #pragma unroll
    for (int m=0;m<4;m++){
      #pragma unroll
      for (int r=0;r<4;r++){
        float h = acc[m][r];
        bufA[(m*16+lk*4+r)*132 + colw] = f2bf(h*sigm(h));
      }
    }
  }
  __syncthreads();

  f32x4 acc[4] = {};
  {
    s16x8 wf[4];
    #pragma unroll
    for (int k0=0;k0<4;k0++) wf[k0] = *(const s16x8*)(w2 + colw*128 + k0*32 + lk*8);
    #pragma unroll
    for (int k0=0;k0<4;k0++){
      #pragma unroll
      for (int m=0;m<4;m++){
        s16x8 a = *(const s16x8*)&bufA[(m*16+lrow)*132 + k0*32 + lk*8];
        acc[m] = MFMA16(a, wf[k0], acc[m]);
      }
    }
  }
  #pragma unroll
  for (int m=0;m<4;m++){
    #pragma unroll
    for (int r=0;r<4;r++){
      float p = acc[m][r]*acc[m][r];
      p += __shfl_xor(p, 1, 64);
      p += __shfl_xor(p, 2, 64);
      p += __shfl_xor(p, 4, 64);
      p += __shfl_xor(p, 8, 64);
      if (lrow == 0) rsum[wv][m*16 + lk*4 + r] = p;
    }
  }
  __syncthreads();
  float gm = gamma[hd*128 + colw] + 1.0f;
  #pragma unroll
  for (int m=0;m<4;m++){
    #pragma unroll
    for (int r=0;r<4;r++){
      int row = m*16 + lk*4 + r;
      float sum = rsum[0][row]+rsum[1][row]+rsum[2][row]+rsum[3][row]
                + rsum[4][row]+rsum[5][row]+rsum[6][row]+rsum[7][row];
      float inv = rsqrtf(sum*(1.0f/128.0f) + 1e-6f);
      float gt = gate[(rowbase+row)*4 + hd];
      outp[(rowbase+row)*512 + hd*128 + colw] = f2bf(acc[m][r]*inv*gm*gt);
    }
  }
}

// ---------------------------------------------------------------------------
extern "C" void kernel_launch(void* const* d_in, const int* in_sizes, int n_in,
                              void* d_out, int out_size, void* d_ws, size_t ws_size,
                              hipStream_t stream)
{
  const float* seq    = (const float*)d_in[0];
  const float* gstore = (const float*)d_in[1];
  const float* gret   = (const float*)d_in[2];
  const float* W_q    = (const float*)d_in[3];
  const float* W_kv   = (const float*)d_in[4];
  const float* W_step = (const float*)d_in[5];
  const float* W_mom  = (const float*)d_in[6];
  const float* W_dec  = (const float*)d_in[7];
  const float* W_gate = (const float*)d_in[8];
  const float* gamma  = (const float*)d_in[9];
  const float* W_o    = (const float*)d_in[10];
  const float* MW1    = (const float*)d_in[11];
  const float* MW2    = (const float*)d_in[12];
  float* out = (float*)d_out;

  const size_t NS = (size_t)16384*512;
  const size_t NG = (size_t)16*64*16384;
  size_t need = (5*NS + 2*NG + 524288 + 262144 + 262144 + 3*16384)*2
              + (2*65536 + 2048)*4;
  if (ws_size < need) return;

  char* ws = (char*)d_ws;
  u16* s_bf = (u16*)ws; ws += NS*2;        // s; reused as outp
  u16* r_bf = (u16*)ws; ws += NS*2;
  u16* kv_bf= (u16*)ws; ws += 2*NS*2;
  u16* q_bf = (u16*)ws; ws += NS*2;
  u16* s1   = (u16*)ws; ws += NG*2;        // -> w1c after k_scan
  u16* s2   = (u16*)ws; ws += NG*2;        // -> w2c
  u16* Wkvt = (u16*)ws; ws += (size_t)524288*2;
  u16* Wqt  = (u16*)ws; ws += (size_t)262144*2;
  u16* Wot  = (u16*)ws; ws += (size_t)262144*2;
  u16* W1tb = (u16*)ws; ws += (size_t)16384*2;
  u16* W2tb = (u16*)ws; ws += (size_t)16384*2;
  u16* W2sb = (u16*)ws; ws += (size_t)16384*2;
  float* lr   = (float*)ws; ws += (size_t)65536*4;
  float* gatep= (float*)ws; ws += (size_t)65536*4;
  float* momv = (float*)ws; ws += 1024*4;
  float* dgv  = (float*)ws; ws += 1024*4;
  u16* outp = s_bf;

  k_prep<<<272, 256, 0, stream>>>(W_kv, W_q, W_o, MW1, MW2, Wkvt, Wqt, Wot, W1tb, W2tb, W2sb);
  k_tokchunk<<<256, 512, 0, stream>>>(seq, gstore, gret, W_step, W_gate, W_dec, W_mom,
                                      s_bf, r_bf, lr, gatep, momv, dgv);
  k_gemm<true><<<dim3(8,128), 256, 0, stream>>>(s_bf, Wkvt, kv_bf, 512, 1024);
  k_gemm<true><<<dim3(4,128), 256, 0, stream>>>(r_bf, Wqt, q_bf, 512, 512);
  k_grad<<<1024, 512, 0, stream>>>(kv_bf, lr, W1tb, W2tb, W2sb, s1, s2);
  k_scan<<<1024, 256, 0, stream>>>(momv, dgv, MW1, MW2, s1, s2);
  k_retr<<<1024, 512, 0, stream>>>(q_bf, s1, s2, gatep, gamma, outp);
  k_gemm<false><<<dim3(4,128), 256, 0, stream>>>(outp, Wot, out, 512, 512);
}

// Round 6
// 205.202 us; speedup vs baseline: 1.1451x; 1.0527x over previous
//
#include <hip/hip_runtime.h>

typedef unsigned short u16;
typedef unsigned int u32;
typedef __attribute__((ext_vector_type(8))) short s16x8;
typedef __attribute__((ext_vector_type(4))) float f32x4;

#define DEV __device__ __forceinline__
#define MFMA16(a,b,c) __builtin_amdgcn_mfma_f32_16x16x32_bf16(a,b,c,0,0,0)

DEV float bf2f(u16 x){ u32 u=((u32)x)<<16; float f; __builtin_memcpy(&f,&u,4); return f; }
DEV u16 f2bf(float f){ u32 u; __builtin_memcpy(&u,&f,4); u32 r=u+0x7FFFu+((u>>16)&1u); return (u16)(r>>16); }
DEV uint4 pack8(const float* f){
  uint4 v;
  v.x=(u32)f2bf(f[0])|((u32)f2bf(f[1])<<16);
  v.y=(u32)f2bf(f[2])|((u32)f2bf(f[3])<<16);
  v.z=(u32)f2bf(f[4])|((u32)f2bf(f[5])<<16);
  v.w=(u32)f2bf(f[6])|((u32)f2bf(f[7])<<16);
  return v;
}
DEV float sigm(float x){ return 1.0f/(1.0f+__expf(-x)); }

// ---------------------------------------------------------------------------
// transpose tile helper: dst[n][k] = bf16(src[k][n]), 64x64 tile, 256 thr
// ---------------------------------------------------------------------------
DEV void trans_tile(const float* src, u16* dst, int K, int Nn, int bx, int by, int tid)
{
  __shared__ float ld[64][65];
  int n0 = bx*64, k0 = by*64;
  #pragma unroll
  for (int rr=0; rr<4; rr++){
    int kk = rr*16 + (tid>>4);
    int nn = (tid&15)*4;
    float4 v = *(const float4*)(src + (size_t)(k0+kk)*Nn + n0 + nn);
    ld[kk][nn]=v.x; ld[kk][nn+1]=v.y; ld[kk][nn+2]=v.z; ld[kk][nn+3]=v.w;
  }
  __syncthreads();
  int nn2 = tid>>2, kb = (tid&3)*16;
  float o[16];
  #pragma unroll
  for (int j=0;j<16;j++) o[j] = ld[kb+j][nn2];
  u16* dp = dst + (size_t)(n0+nn2)*K + k0 + kb;
  *(uint4*)dp     = pack8(&o[0]);
  *(uint4*)(dp+8) = pack8(&o[8]);
}

// merged weight prep
__global__ __launch_bounds__(256) void k_prep(const float* __restrict__ Wkv,
    const float* __restrict__ Wq, const float* __restrict__ Wo,
    const float* __restrict__ MW1, const float* __restrict__ MW2,
    u16* __restrict__ Wkvt, u16* __restrict__ Wqt, u16* __restrict__ Wot,
    u16* __restrict__ W1t, u16* __restrict__ W2t, u16* __restrict__ W2s)
{
  int blk = blockIdx.x, tid = threadIdx.x;
  if (blk < 128)      trans_tile(Wkv, Wkvt, 512, 1024, blk&15, blk>>4, tid);
  else if (blk < 192){ int l = blk-128; trans_tile(Wq, Wqt, 512, 512, l&7, l>>3, tid); }
  else if (blk < 256){ int l = blk-192; trans_tile(Wo, Wot, 512, 512, l&7, l>>3, tid); }
  else if (blk < 260){ int l = blk-256; trans_tile(MW1, W1t, 128, 128, l&1, l>>1, tid); }
  else if (blk < 264){ int l = blk-260; trans_tile(MW2, W2t, 128, 128, l&1, l>>1, tid); }
  else {
    int e = ((blk-264)*256 + tid)*8;
    float f[8];
    *(float4*)&f[0] = *(const float4*)(MW2+e);
    *(float4*)&f[4] = *(const float4*)(MW2+e+4);
    *(uint4*)(W2s+e) = pack8(f);
  }
}

// ---------------------------------------------------------------------------
// K1: merged per-token rmsnorm + chunk mean -> gates. 512 thr per (b,chunk).
// ---------------------------------------------------------------------------
__global__ __launch_bounds__(512) void k_tokchunk(const float* __restrict__ seq,
    const float* __restrict__ gs, const float* __restrict__ gr,
    const float* __restrict__ Wstep, const float* __restrict__ Wgate,
    const float* __restrict__ Wdec, const float* __restrict__ Wmom,
    u16* __restrict__ s, u16* __restrict__ r,
    float* __restrict__ lr, float* __restrict__ gate,
    float* __restrict__ momv, float* __restrict__ dgv)
{
  __shared__ float pchunk[8][512];
  __shared__ float red[8][512];
  const int blk = blockIdx.x;
  const int b = blk >> 6, ci = blk & 63;
  const int tid = threadIdx.x;
  const int wv = tid >> 6, lane = tid & 63;
  const size_t rowbase = (size_t)b*4096 + (size_t)ci*64;

  float psum[8] = {0,0,0,0,0,0,0,0};
  #pragma unroll 1
  for (int tt=0; tt<8; tt++){
    int t = wv*8 + tt;
    const float* row = seq + (rowbase + t)*512;
    float x[8];
    *(float4*)&x[0] = *(const float4*)(row + lane*8);
    *(float4*)&x[4] = *(const float4*)(row + lane*8 + 4);
    float ss = 0.f;
    #pragma unroll
    for (int j=0;j<8;j++) ss += x[j]*x[j];
    #pragma unroll
    for (int o=32;o>=1;o>>=1) ss += __shfl_xor(ss, o, 64);
    float inv = rsqrtf(ss*(1.0f/512.0f) + 1e-6f);
    float al[4] = {0,0,0,0}, ag[4] = {0,0,0,0};
    float sv8[8], rv8[8];
    #pragma unroll
    for (int j=0;j<8;j++){
      int d = lane*8 + j;
      float sn = x[j]*inv;
      float sv = sn*gs[d];
      float rv = sn*gr[d];
      sv8[j]=sv; rv8[j]=rv;
      psum[j] += sv;
      float4 wst = *(const float4*)(Wstep + d*4);
      float4 wgt = *(const float4*)(Wgate + d*4);
      al[0]+=sv*wst.x; al[1]+=sv*wst.y; al[2]+=sv*wst.z; al[3]+=sv*wst.w;
      ag[0]+=rv*wgt.x; ag[1]+=rv*wgt.y; ag[2]+=rv*wgt.z; ag[3]+=rv*wgt.w;
    }
    *(uint4*)(s + (rowbase+t)*512 + lane*8) = pack8(sv8);
    *(uint4*)(r + (rowbase+t)*512 + lane*8) = pack8(rv8);
    #pragma unroll
    for (int o=32;o>=1;o>>=1){
      #pragma unroll
      for (int h=0;h<4;h++){ al[h] += __shfl_xor(al[h], o, 64); ag[h] += __shfl_xor(ag[h], o, 64); }
    }
    if (lane == 0){
      #pragma unroll
      for (int h=0;h<4;h++){
        lr[(rowbase+t)*4 + h]   = sigm(al[h]);
        gate[(rowbase+t)*4 + h] = sigm(ag[h]);
      }
    }
  }
  #pragma unroll
  for (int j=0;j<8;j++) pchunk[wv][lane*8+j] = psum[j];
  __syncthreads();
  {
    int d = tid;
    float mean = 0.f;
    #pragma unroll
    for (int w=0;w<8;w++) mean += pchunk[w][d];
    mean *= (1.0f/64.0f);
    #pragma unroll
    for (int h=0;h<4;h++){
      red[h][d]   = mean*Wdec[d*4+h];
      red[4+h][d] = mean*Wmom[d*4+h];
    }
  }
  __syncthreads();
  {
    float sum = 0.f;
    #pragma unroll
    for (int j=0;j<8;j++) sum += red[wv][lane*8+j];
    #pragma unroll
    for (int o=32;o>=1;o>>=1) sum += __shfl_xor(sum, o, 64);
    if (lane == 0){
      if (wv < 4) dgv[((size_t)(b*4+wv))*64 + ci]     = 1.0f - sigm(sum);
      else        momv[((size_t)(b*4+(wv-4)))*64 + ci] = sigm(sum);
    }
  }
}

// ---------------------------------------------------------------------------
// K3: MFMA GEMM, m97 structure (unchanged from r5).
// ---------------------------------------------------------------------------
template<bool OUT_BF>
__global__ __launch_bounds__(256) void k_gemm(const u16* __restrict__ A,
    const u16* __restrict__ Bt, void* __restrict__ Cv, int K, int ldc)
{
  __shared__ u16 sA[128*64];
  __shared__ u16 sB[128*64];
  const int tid = threadIdx.x;
  const int wv = tid>>6, lane = tid&63, lrow = lane&15, lk = lane>>4;
  const int wm = (wv>>1)*64, wn = (wv&1)*64;
  const int rowbase = blockIdx.y*128, colbase = blockIdx.x*128;
  const int srow = lane>>3;
  const int scol = (lane&7)*8;
  f32x4 acc[4][4] = {};
  for (int kc = 0; kc < K; kc += 64){
    __syncthreads();
    #pragma unroll
    for (int it=0; it<4; ++it){
      int seg = it*4 + wv;
      int row = seg*8 + srow;
      __builtin_amdgcn_global_load_lds(
        (const __attribute__((address_space(1))) void*)(A + (size_t)(rowbase+row)*K + kc + scol),
        (__attribute__((address_space(3))) void*)&sA[seg*512 + lane*8], 16, 0, 0);
      __builtin_amdgcn_global_load_lds(
        (const __attribute__((address_space(1))) void*)(Bt + (size_t)(colbase+row)*K + kc + scol),
        (__attribute__((address_space(3))) void*)&sB[seg*512 + lane*8], 16, 0, 0);
    }
    __syncthreads();
    #pragma unroll
    for (int k0=0;k0<2;k0++){
      s16x8 a[4], b[4];
      #pragma unroll
      for (int m=0;m<4;m++) a[m] = *(const s16x8*)&sA[(wm+m*16+lrow)*64 + k0*32 + lk*8];
      #pragma unroll
      for (int n=0;n<4;n++) b[n] = *(const s16x8*)&sB[(wn+n*16+lrow)*64 + k0*32 + lk*8];
      #pragma unroll
      for (int m=0;m<4;m++)
        #pragma unroll
        for (int n=0;n<4;n++)
          acc[m][n] = MFMA16(a[m], b[n], acc[m][n]);
    }
  }
  #pragma unroll
  for (int m=0;m<4;m++)
    #pragma unroll
    for (int n=0;n<4;n++)
      #pragma unroll
      for (int r=0;r<4;r++){
        int row = rowbase + wm + m*16 + lk*4 + r;
        int col = colbase + wn + n*16 + lrow;
        float v = acc[m][n][r];
        if (OUT_BF) ((u16*)Cv)[(size_t)row*ldc + col] = f2bf(v);
        else        ((float*)Cv)[(size_t)row*ldc + col] = v;
      }
}

// ---------------------------------------------------------------------------
// K4: per-chunk gradient. 256 thr / 4 waves, ~50.8KB LDS -> 3 blocks/CU.
// kct B-frags and v values prefetched to registers at stage0 (no bufKt).
// ---------------------------------------------------------------------------
__global__ __launch_bounds__(256) void k_grad(const u16* __restrict__ kv,
    const float* __restrict__ lr, const u16* __restrict__ W1t,
    const u16* __restrict__ W2t, const u16* __restrict__ W2s,
    u16* __restrict__ s1, u16* __restrict__ s2)
{
  __shared__ u16 bufR[64*132];   // kc -> As -> dP (row-major)
  __shared__ u16 bufAt[128*68];  // Ast -> dHt
  __shared__ u16 bufPt[128*68];  // dPt
  __shared__ float lrs[64];

  const int blk = blockIdx.x;
  const int bhi = blk >> 6, ci = blk & 63;
  const int b = bhi >> 2, hd = bhi & 3;
  const int tid = threadIdx.x;
  const int wv = tid>>6, lane = tid&63, lrow = lane&15, lk = lane>>4;
  int col[2]; col[0] = wv*32 + lrow; col[1] = wv*32 + 16 + lrow;
  const size_t rowbase = (size_t)b*4096 + (size_t)ci*64;

  // ---- stage0: kc rows -> bufR; prefetch v and kct fragments to registers
  #pragma unroll
  for (int rep=0;rep<4;rep++){
    int lin = rep*2048 + tid*8;
    int i = lin >> 7, d = lin & 127;
    *(uint4*)&bufR[i*132 + d] = *(const uint4*)(kv + (rowbase + i)*1024 + hd*128 + d);
  }
  if (tid < 64) lrs[tid] = lr[(rowbase + tid)*4 + hd] * (2.0f/128.0f);
  u16 vreg[2][4][4];     // [n][m][r]: v[row][col[n]]
  #pragma unroll
  for (int n=0;n<2;n++)
    #pragma unroll
    for (int m=0;m<4;m++)
      #pragma unroll
      for (int r=0;r<4;r++)
        vreg[n][m][r] = kv[(rowbase + m*16 + lk*4 + r)*1024 + 512 + hd*128 + col[n]];
  s16x8 kbf[2][2];       // [n][k0]: kct B-frags = kc[i][col[n]], i = k0*32+lk*8+j
  #pragma unroll
  for (int n=0;n<2;n++)
    #pragma unroll
    for (int k0=0;k0<2;k0++)
      #pragma unroll
      for (int j=0;j<8;j++)
        ((u16*)&kbf[n][k0])[j] = kv[(rowbase + k0*32 + lk*8 + j)*1024 + hd*128 + col[n]];
  __syncthreads();

  float spv[4][2][4];

  // ---- mm1: H = kc @ W1 ; A = silu(H)
  {
    s16x8 wf[2][4];
    #pragma unroll
    for (int n=0;n<2;n++)
      #pragma unroll
      for (int k0=0;k0<4;k0++) wf[n][k0] = *(const s16x8*)(W1t + col[n]*128 + k0*32 + lk*8);
    f32x4 acc[4][2] = {};
    #pragma unroll
    for (int k0=0;k0<4;k0++)
      #pragma unroll
      for (int m=0;m<4;m++){
        s16x8 a = *(const s16x8*)&bufR[(m*16+lrow)*132 + k0*32 + lk*8];
        #pragma unroll
        for (int n=0;n<2;n++) acc[m][n] = MFMA16(a, wf[n][k0], acc[m][n]);
      }
    __syncthreads();   // kc reads complete block-wide
    #pragma unroll
    for (int m=0;m<4;m++)
      #pragma unroll
      for (int n=0;n<2;n++){
        int row0 = m*16 + lk*4;
        u16 av4[4];
        #pragma unroll
        for (int r=0;r<4;r++){
          float h = acc[m][n][r];
          float sg = sigm(h);
          av4[r] = f2bf(h*sg);
          spv[m][n][r] = sg*(1.0f + h*(1.0f - sg));
          bufR[(row0+r)*132 + col[n]] = av4[r];
        }
        *(uint2*)&bufAt[col[n]*68 + row0] = make_uint2(
          (u32)av4[0] | ((u32)av4[1]<<16), (u32)av4[2] | ((u32)av4[3]<<16));
      }
  }
  __syncthreads();

  // ---- mm2: P = A @ W2 ; dP = lr*(P - v)
  {
    s16x8 wf[2][4];
    #pragma unroll
    for (int n=0;n<2;n++)
      #pragma unroll
      for (int k0=0;k0<4;k0++) wf[n][k0] = *(const s16x8*)(W2t + col[n]*128 + k0*32 + lk*8);
    f32x4 acc[4][2] = {};
    #pragma unroll
    for (int k0=0;k0<4;k0++)
      #pragma unroll
      for (int m=0;m<4;m++){
        s16x8 a = *(const s16x8*)&bufR[(m*16+lrow)*132 + k0*32 + lk*8];
        #pragma unroll
        for (int n=0;n<2;n++) acc[m][n] = MFMA16(a, wf[n][k0], acc[m][n]);
      }
    __syncthreads();   // As reads complete
    #pragma unroll
    for (int m=0;m<4;m++)
      #pragma unroll
      for (int n=0;n<2;n++){
        int row0 = m*16 + lk*4;
        u16 dp4[4];
        #pragma unroll
        for (int r=0;r<4;r++){
          int row = row0 + r;
          float vv = bf2f(vreg[n][m][r]);
          float dp = lrs[row]*(acc[m][n][r] - vv);
          dp4[r] = f2bf(dp);
          bufR[row*132 + col[n]] = dp4[r];
        }
        *(uint2*)&bufPt[col[n]*68 + row0] = make_uint2(
          (u32)dp4[0] | ((u32)dp4[1]<<16), (u32)dp4[2] | ((u32)dp4[3]<<16));
      }
  }
  __syncthreads();

  const size_t outbase = (size_t)blk * 16384;

  // ---- mm3: dA = dP @ W2^T (regs)
  f32x4 da[4][2] = {};
  {
    s16x8 wf[2][4];
    #pragma unroll
    for (int n=0;n<2;n++)
      #pragma unroll
      for (int k0=0;k0<4;k0++) wf[n][k0] = *(const s16x8*)(W2s + col[n]*128 + k0*32 + lk*8);
    #pragma unroll
    for (int k0=0;k0<4;k0++)
      #pragma unroll
      for (int m=0;m<4;m++){
        s16x8 a = *(const s16x8*)&bufR[(m*16+lrow)*132 + k0*32 + lk*8];
        #pragma unroll
        for (int n=0;n<2;n++) da[m][n] = MFMA16(a, wf[n][k0], da[m][n]);
      }
  }
  // ---- mm4: s2t[d_out][d_h] = -(dPt x Ast)
  {
    f32x4 acc[8][2] = {};
    #pragma unroll
    for (int k0=0;k0<2;k0++){
      s16x8 bf0 = *(const s16x8*)&bufAt[col[0]*68 + k0*32 + lk*8];
      s16x8 bf1 = *(const s16x8*)&bufAt[col[1]*68 + k0*32 + lk*8];
      #pragma unroll
      for (int m=0;m<8;m++){
        s16x8 a = *(const s16x8*)&bufPt[(m*16+lrow)*68 + k0*32 + lk*8];
        acc[m][0] = MFMA16(a, bf0, acc[m][0]);
        acc[m][1] = MFMA16(a, bf1, acc[m][1]);
      }
    }
    #pragma unroll
    for (int m=0;m<8;m++)
      #pragma unroll
      for (int n=0;n<2;n++)
        #pragma unroll
        for (int r=0;r<4;r++)
          s2[outbase + (size_t)(m*16 + lk*4 + r)*128 + col[n]] = f2bf(-acc[m][n][r]);
  }
  __syncthreads();   // bufAt reads (mm4) complete before overwrite
  // dHt = spv * dA -> bufAt
  #pragma unroll
  for (int m=0;m<4;m++)
    #pragma unroll
    for (int n=0;n<2;n++){
      int row0 = m*16 + lk*4;
      u16 dh4[4];
      #pragma unroll
      for (int r=0;r<4;r++) dh4[r] = f2bf(spv[m][n][r]*da[m][n][r]);
      *(uint2*)&bufAt[col[n]*68 + row0] = make_uint2(
        (u32)dh4[0] | ((u32)dh4[1]<<16), (u32)dh4[2] | ((u32)dh4[3]<<16));
    }
  __syncthreads();

  // ---- mm5: s1t[d_h][d_in] = -(dHt x kct); B-op from registers (kbf)
  {
    f32x4 acc[8][2] = {};
    #pragma unroll
    for (int k0=0;k0<2;k0++)
      #pragma unroll
      for (int m=0;m<8;m++){
        s16x8 a = *(const s16x8*)&bufAt[(m*16+lrow)*68 + k0*32 + lk*8];
        acc[m][0] = MFMA16(a, kbf[0][k0], acc[m][0]);
        acc[m][1] = MFMA16(a, kbf[1][k0], acc[m][1]);
      }
    #pragma unroll
    for (int m=0;m<8;m++)
      #pragma unroll
      for (int n=0;n<2;n++)
        #pragma unroll
        for (int r=0;r<4;r++)
          s1[outbase + (size_t)(m*16 + lk*4 + r)*128 + col[n]] = f2bf(-acc[m][n][r]);
  }
}

// ---------------------------------------------------------------------------
// K5: fused momentum + decay scans; unroll 4 for load-latency overlap.
// ---------------------------------------------------------------------------
__global__ __launch_bounds__(256) void k_scan(const float* __restrict__ momv,
    const float* __restrict__ dgv, const float* __restrict__ MW1,
    const float* __restrict__ MW2, u16* __restrict__ s1w, u16* __restrict__ s2w)
{
  int bhi = blockIdx.x >> 6, eb = blockIdx.x & 63;
  int e = eb*256 + threadIdx.x;
  float u1 = MW1[(e&127)*128 + (e>>7)];
  float u2 = MW2[(e&127)*128 + (e>>7)];
  float m1 = 0.f, m2 = 0.f;
  size_t base = (size_t)bhi*64*16384 + e;
  #pragma unroll 4
  for (int t=0; t<64; t++){
    float g  = momv[bhi*64 + t];
    float dg = dgv[bhi*64 + t];
    size_t idx = base + (size_t)t*16384;
    float g1v = bf2f(s1w[idx]);
    float g2v = bf2f(s2w[idx]);
    s1w[idx] = f2bf(u1);
    s2w[idx] = f2bf(u2);
    m1 = g*m1 + g1v;
    m2 = g*m2 + g2v;
    u1 = dg*u1 + m1;
    u2 = dg*u2 + m2;
  }
}

// ---------------------------------------------------------------------------
// K6: retrieval (unchanged from r5).
// ---------------------------------------------------------------------------
__global__ __launch_bounds__(512) void k_retr(const u16* __restrict__ qin,
    const u16* __restrict__ w1c, const u16* __restrict__ w2c,
    const float* __restrict__ gate, const float* __restrict__ gamma,
    u16* __restrict__ outp)
{
  __shared__ u16 bufA[64*132];
  __shared__ float rsum[8][64];
  const int blk = blockIdx.x;
  const int bhi = blk >> 6, ci = blk & 63;
  const int b = bhi >> 2, hd = bhi & 3;
  const int tid = threadIdx.x;
  const int wv = tid>>6, lane = tid&63, lrow = lane&15, lk = lane>>4;
  const int nb = wv*16;
  const int colw = nb + lrow;
  const size_t rowbase = (size_t)b*4096 + (size_t)ci*64;
  const u16* w1 = w1c + (size_t)blk*16384;
  const u16* w2 = w2c + (size_t)blk*16384;

  {
    s16x8 wf[4];
    #pragma unroll
    for (int k0=0;k0<4;k0++) wf[k0] = *(const s16x8*)(w1 + colw*128 + k0*32 + lk*8);
    f32x4 acc[4] = {};
    #pragma unroll
    for (int k0=0;k0<4;k0++){
      #pragma unroll
      for (int m=0;m<4;m++){
        s16x8 a = *(const s16x8*)(qin + (rowbase + m*16+lrow)*512 + hd*128 + k0*32 + lk*8);
        acc[m] = MFMA16(a, wf[k0], acc[m]);
      }
    }
    #pragma unroll
    for (int m=0;m<4;m++){
      #pragma unroll
      for (int r=0;r<4;r++){
        float h = acc[m][r];
        bufA[(m*16+lk*4+r)*132 + colw] = f2bf(h*sigm(h));
      }
    }
  }
  __syncthreads();

  f32x4 acc[4] = {};
  {
    s16x8 wf[4];
    #pragma unroll
    for (int k0=0;k0<4;k0++) wf[k0] = *(const s16x8*)(w2 + colw*128 + k0*32 + lk*8);
    #pragma unroll
    for (int k0=0;k0<4;k0++){
      #pragma unroll
      for (int m=0;m<4;m++){
        s16x8 a = *(const s16x8*)&bufA[(m*16+lrow)*132 + k0*32 + lk*8];
        acc[m] = MFMA16(a, wf[k0], acc[m]);
      }
    }
  }
  #pragma unroll
  for (int m=0;m<4;m++){
    #pragma unroll
    for (int r=0;r<4;r++){
      float p = acc[m][r]*acc[m][r];
      p += __shfl_xor(p, 1, 64);
      p += __shfl_xor(p, 2, 64);
      p += __shfl_xor(p, 4, 64);
      p += __shfl_xor(p, 8, 64);
      if (lrow == 0) rsum[wv][m*16 + lk*4 + r] = p;
    }
  }
  __syncthreads();
  float gm = gamma[hd*128 + colw] + 1.0f;
  #pragma unroll
  for (int m=0;m<4;m++){
    #pragma unroll
    for (int r=0;r<4;r++){
      int row = m*16 + lk*4 + r;
      float sum = rsum[0][row]+rsum[1][row]+rsum[2][row]+rsum[3][row]
                + rsum[4][row]+rsum[5][row]+rsum[6][row]+rsum[7][row];
      float inv = rsqrtf(sum*(1.0f/128.0f) + 1e-6f);
      float gt = gate[(rowbase+row)*4 + hd];
      outp[(rowbase+row)*512 + hd*128 + colw] = f2bf(acc[m][r]*inv*gm*gt);
    }
  }
}

// ---------------------------------------------------------------------------
extern "C" void kernel_launch(void* const* d_in, const int* in_sizes, int n_in,
                              void* d_out, int out_size, void* d_ws, size_t ws_size,
                              hipStream_t stream)
{
  const float* seq    = (const float*)d_in[0];
  const float* gstore = (const float*)d_in[1];
  const float* gret   = (const float*)d_in[2];
  const float* W_q    = (const float*)d_in[3];
  const float* W_kv   = (const float*)d_in[4];
  const float* W_step = (const float*)d_in[5];
  const float* W_mom  = (const float*)d_in[6];
  const float* W_dec  = (const float*)d_in[7];
  const float* W_gate = (const float*)d_in[8];
  const float* gamma  = (const float*)d_in[9];
  const float* W_o    = (const float*)d_in[10];
  const float* MW1    = (const float*)d_in[11];
  const float* MW2    = (const float*)d_in[12];
  float* out = (float*)d_out;

  const size_t NS = (size_t)16384*512;
  const size_t NG = (size_t)16*64*16384;
  size_t need = (5*NS + 2*NG + 524288 + 262144 + 262144 + 3*16384)*2
              + (2*65536 + 2048)*4;
  if (ws_size < need) return;

  char* ws = (char*)d_ws;
  u16* s_bf = (u16*)ws; ws += NS*2;        // s; reused as outp
  u16* r_bf = (u16*)ws; ws += NS*2;
  u16* kv_bf= (u16*)ws; ws += 2*NS*2;
  u16* q_bf = (u16*)ws; ws += NS*2;
  u16* s1   = (u16*)ws; ws += NG*2;        // -> w1c after k_scan
  u16* s2   = (u16*)ws; ws += NG*2;        // -> w2c
  u16* Wkvt = (u16*)ws; ws += (size_t)524288*2;
  u16* Wqt  = (u16*)ws; ws += (size_t)262144*2;
  u16* Wot  = (u16*)ws; ws += (size_t)262144*2;
  u16* W1tb = (u16*)ws; ws += (size_t)16384*2;
  u16* W2tb = (u16*)ws; ws += (size_t)16384*2;
  u16* W2sb = (u16*)ws; ws += (size_t)16384*2;
  float* lr   = (float*)ws; ws += (size_t)65536*4;
  float* gatep= (float*)ws; ws += (size_t)65536*4;
  float* momv = (float*)ws; ws += 1024*4;
  float* dgv  = (float*)ws; ws += 1024*4;
  u16* outp = s_bf;

  k_prep<<<272, 256, 0, stream>>>(W_kv, W_q, W_o, MW1, MW2, Wkvt, Wqt, Wot, W1tb, W2tb, W2sb);
  k_tokchunk<<<256, 512, 0, stream>>>(seq, gstore, gret, W_step, W_gate, W_dec, W_mom,
                                      s_bf, r_bf, lr, gatep, momv, dgv);
  k_gemm<true><<<dim3(8,128), 256, 0, stream>>>(s_bf, Wkvt, kv_bf, 512, 1024);
  k_gemm<true><<<dim3(4,128), 256, 0, stream>>>(r_bf, Wqt, q_bf, 512, 512);
  k_grad<<<1024, 256, 0, stream>>>(kv_bf, lr, W1tb, W2tb, W2sb, s1, s2);
  k_scan<<<1024, 256, 0, stream>>>(momv, dgv, MW1, MW2, s1, s2);
  k_retr<<<1024, 512, 0, stream>>>(q_bf, s1, s2, gatep, gamma, outp);
  k_gemm<false><<<dim3(4,128), 256, 0, stream>>>(outp, Wot, out, 512, 512);
}

// Round 7
// 174.472 us; speedup vs baseline: 1.3468x; 1.1761x over previous
//
#include <hip/hip_runtime.h>

typedef unsigned short u16;
typedef unsigned int u32;
typedef __attribute__((ext_vector_type(8))) short s16x8;
typedef __attribute__((ext_vector_type(4))) float f32x4;

#define DEV __device__ __forceinline__
#define MFMA16(a,b,c) __builtin_amdgcn_mfma_f32_16x16x32_bf16(a,b,c,0,0,0)

DEV float bf2f(u16 x){ u32 u=((u32)x)<<16; float f; __builtin_memcpy(&f,&u,4); return f; }
DEV u16 f2bf(float f){ u32 u; __builtin_memcpy(&u,&f,4); u32 r=u+0x7FFFu+((u>>16)&1u); return (u16)(r>>16); }
DEV uint4 pack8(const float* f){
  uint4 v;
  v.x=(u32)f2bf(f[0])|((u32)f2bf(f[1])<<16);
  v.y=(u32)f2bf(f[2])|((u32)f2bf(f[3])<<16);
  v.z=(u32)f2bf(f[4])|((u32)f2bf(f[5])<<16);
  v.w=(u32)f2bf(f[6])|((u32)f2bf(f[7])<<16);
  return v;
}
DEV float sigm(float x){ return 1.0f/(1.0f+__expf(-x)); }

// ---------------------------------------------------------------------------
// transpose tile helper: dst[n][k] = bf16(src[k][n]), 64x64 tile, 256 thr
// ---------------------------------------------------------------------------
DEV void trans_tile(const float* src, u16* dst, int K, int Nn, int bx, int by, int tid)
{
  __shared__ float ld[64][65];
  int n0 = bx*64, k0 = by*64;
  #pragma unroll
  for (int rr=0; rr<4; rr++){
    int kk = rr*16 + (tid>>4);
    int nn = (tid&15)*4;
    float4 v = *(const float4*)(src + (size_t)(k0+kk)*Nn + n0 + nn);
    ld[kk][nn]=v.x; ld[kk][nn+1]=v.y; ld[kk][nn+2]=v.z; ld[kk][nn+3]=v.w;
  }
  __syncthreads();
  int nn2 = tid>>2, kb = (tid&3)*16;
  float o[16];
  #pragma unroll
  for (int j=0;j<16;j++) o[j] = ld[kb+j][nn2];
  u16* dp = dst + (size_t)(n0+nn2)*K + k0 + kb;
  *(uint4*)dp     = pack8(&o[0]);
  *(uint4*)(dp+8) = pack8(&o[8]);
}

// merged weight prep
__global__ __launch_bounds__(256) void k_prep(const float* __restrict__ Wkv,
    const float* __restrict__ Wq, const float* __restrict__ Wo,
    const float* __restrict__ MW1, const float* __restrict__ MW2,
    u16* __restrict__ Wkvt, u16* __restrict__ Wqt, u16* __restrict__ Wot,
    u16* __restrict__ W1t, u16* __restrict__ W2t, u16* __restrict__ W2s)
{
  int blk = blockIdx.x, tid = threadIdx.x;
  if (blk < 128)      trans_tile(Wkv, Wkvt, 512, 1024, blk&15, blk>>4, tid);
  else if (blk < 192){ int l = blk-128; trans_tile(Wq, Wqt, 512, 512, l&7, l>>3, tid); }
  else if (blk < 256){ int l = blk-192; trans_tile(Wo, Wot, 512, 512, l&7, l>>3, tid); }
  else if (blk < 260){ int l = blk-256; trans_tile(MW1, W1t, 128, 128, l&1, l>>1, tid); }
  else if (blk < 264){ int l = blk-260; trans_tile(MW2, W2t, 128, 128, l&1, l>>1, tid); }
  else {
    int e = ((blk-264)*256 + tid)*8;
    float f[8];
    *(float4*)&f[0] = *(const float4*)(MW2+e);
    *(float4*)&f[4] = *(const float4*)(MW2+e+4);
    *(uint4*)(W2s+e) = pack8(f);
  }
}

// ---------------------------------------------------------------------------
// K1: merged per-token rmsnorm + chunk mean -> gates. 512 thr per (b,chunk).
// ---------------------------------------------------------------------------
__global__ __launch_bounds__(512) void k_tokchunk(const float* __restrict__ seq,
    const float* __restrict__ gs, const float* __restrict__ gr,
    const float* __restrict__ Wstep, const float* __restrict__ Wgate,
    const float* __restrict__ Wdec, const float* __restrict__ Wmom,
    u16* __restrict__ s, u16* __restrict__ r,
    float* __restrict__ lr, float* __restrict__ gate,
    float* __restrict__ momv, float* __restrict__ dgv)
{
  __shared__ float pchunk[8][512];
  __shared__ float red[8][512];
  const int blk = blockIdx.x;
  const int b = blk >> 6, ci = blk & 63;
  const int tid = threadIdx.x;
  const int wv = tid >> 6, lane = tid & 63;
  const size_t rowbase = (size_t)b*4096 + (size_t)ci*64;

  float psum[8] = {0,0,0,0,0,0,0,0};
  #pragma unroll 1
  for (int tt=0; tt<8; tt++){
    int t = wv*8 + tt;
    const float* row = seq + (rowbase + t)*512;
    float x[8];
    *(float4*)&x[0] = *(const float4*)(row + lane*8);
    *(float4*)&x[4] = *(const float4*)(row + lane*8 + 4);
    float ss = 0.f;
    #pragma unroll
    for (int j=0;j<8;j++) ss += x[j]*x[j];
    #pragma unroll
    for (int o=32;o>=1;o>>=1) ss += __shfl_xor(ss, o, 64);
    float inv = rsqrtf(ss*(1.0f/512.0f) + 1e-6f);
    float al[4] = {0,0,0,0}, ag[4] = {0,0,0,0};
    float sv8[8], rv8[8];
    #pragma unroll
    for (int j=0;j<8;j++){
      int d = lane*8 + j;
      float sn = x[j]*inv;
      float sv = sn*gs[d];
      float rv = sn*gr[d];
      sv8[j]=sv; rv8[j]=rv;
      psum[j] += sv;
      float4 wst = *(const float4*)(Wstep + d*4);
      float4 wgt = *(const float4*)(Wgate + d*4);
      al[0]+=sv*wst.x; al[1]+=sv*wst.y; al[2]+=sv*wst.z; al[3]+=sv*wst.w;
      ag[0]+=rv*wgt.x; ag[1]+=rv*wgt.y; ag[2]+=rv*wgt.z; ag[3]+=rv*wgt.w;
    }
    *(uint4*)(s + (rowbase+t)*512 + lane*8) = pack8(sv8);
    *(uint4*)(r + (rowbase+t)*512 + lane*8) = pack8(rv8);
    #pragma unroll
    for (int o=32;o>=1;o>>=1){
      #pragma unroll
      for (int h=0;h<4;h++){ al[h] += __shfl_xor(al[h], o, 64); ag[h] += __shfl_xor(ag[h], o, 64); }
    }
    if (lane == 0){
      #pragma unroll
      for (int h=0;h<4;h++){
        lr[(rowbase+t)*4 + h]   = sigm(al[h]);
        gate[(rowbase+t)*4 + h] = sigm(ag[h]);
      }
    }
  }
  #pragma unroll
  for (int j=0;j<8;j++) pchunk[wv][lane*8+j] = psum[j];
  __syncthreads();
  {
    int d = tid;
    float mean = 0.f;
    #pragma unroll
    for (int w=0;w<8;w++) mean += pchunk[w][d];
    mean *= (1.0f/64.0f);
    #pragma unroll
    for (int h=0;h<4;h++){
      red[h][d]   = mean*Wdec[d*4+h];
      red[4+h][d] = mean*Wmom[d*4+h];
    }
  }
  __syncthreads();
  {
    float sum = 0.f;
    #pragma unroll
    for (int j=0;j<8;j++) sum += red[wv][lane*8+j];
    #pragma unroll
    for (int o=32;o>=1;o>>=1) sum += __shfl_xor(sum, o, 64);
    if (lane == 0){
      if (wv < 4) dgv[((size_t)(b*4+wv))*64 + ci]     = 1.0f - sigm(sum);
      else        momv[((size_t)(b*4+(wv-4)))*64 + ci] = sigm(sum);
    }
  }
}

// ---------------------------------------------------------------------------
// GEMM tile body (m97 structure). bx,by precomputed by caller wrapper.
// ---------------------------------------------------------------------------
template<bool OUT_BF>
DEV void gemm_body(const u16* A, const u16* Bt, void* Cv, int K, int ldc,
                   int bx, int by, u16* sA, u16* sB)
{
  const int tid = threadIdx.x;
  const int wv = tid>>6, lane = tid&63, lrow = lane&15, lk = lane>>4;
  const int wm = (wv>>1)*64, wn = (wv&1)*64;
  const int rowbase = by*128, colbase = bx*128;
  const int srow = lane>>3;
  const int scol = (lane&7)*8;
  f32x4 acc[4][4] = {};
  for (int kc = 0; kc < K; kc += 64){
    __syncthreads();
    #pragma unroll
    for (int it=0; it<4; ++it){
      int seg = it*4 + wv;
      int row = seg*8 + srow;
      __builtin_amdgcn_global_load_lds(
        (const __attribute__((address_space(1))) void*)(A + (size_t)(rowbase+row)*K + kc + scol),
        (__attribute__((address_space(3))) void*)&sA[seg*512 + lane*8], 16, 0, 0);
      __builtin_amdgcn_global_load_lds(
        (const __attribute__((address_space(1))) void*)(Bt + (size_t)(colbase+row)*K + kc + scol),
        (__attribute__((address_space(3))) void*)&sB[seg*512 + lane*8], 16, 0, 0);
    }
    __syncthreads();
    #pragma unroll
    for (int k0=0;k0<2;k0++){
      s16x8 a[4], b[4];
      #pragma unroll
      for (int m=0;m<4;m++) a[m] = *(const s16x8*)&sA[(wm+m*16+lrow)*64 + k0*32 + lk*8];
      #pragma unroll
      for (int n=0;n<4;n++) b[n] = *(const s16x8*)&sB[(wn+n*16+lrow)*64 + k0*32 + lk*8];
      #pragma unroll
      for (int m=0;m<4;m++)
        #pragma unroll
        for (int n=0;n<4;n++)
          acc[m][n] = MFMA16(a[m], b[n], acc[m][n]);
    }
  }
  #pragma unroll
  for (int m=0;m<4;m++)
    #pragma unroll
    for (int n=0;n<4;n++)
      #pragma unroll
      for (int r=0;r<4;r++){
        int row = rowbase + wm + m*16 + lk*4 + r;
        int col = colbase + wn + n*16 + lrow;
        float v = acc[m][n][r];
        if (OUT_BF) ((u16*)Cv)[(size_t)row*ldc + col] = f2bf(v);
        else        ((float*)Cv)[(size_t)row*ldc + col] = v;
      }
}

// merged kv + q GEMM: blocks [0,1024) kv (nbx=8), [1024,1536) q (nbx=4).
// XCD-swizzled within each range.
__global__ __launch_bounds__(256) void k_gemmAB(const u16* __restrict__ A1,
    const u16* __restrict__ B1, u16* __restrict__ C1,
    const u16* __restrict__ A2, const u16* __restrict__ B2, u16* __restrict__ C2)
{
  __shared__ u16 sA[128*64];
  __shared__ u16 sB[128*64];
  int bid = blockIdx.x;
  if (bid < 1024){
    int s = (bid & 7)*128 + (bid >> 3);
    gemm_body<true>(A1, B1, C1, 512, 1024, s & 7, s >> 3, sA, sB);
  } else {
    int l = bid - 1024;
    int s = (l & 7)*64 + (l >> 3);
    gemm_body<true>(A2, B2, C2, 512, 512, s & 3, s >> 2, sA, sB);
  }
}

// single GEMM (out-projection), 1D grid, swizzled. nbx = N/128.
template<bool OUT_BF>
__global__ __launch_bounds__(256) void k_gemm1(const u16* __restrict__ A,
    const u16* __restrict__ Bt, void* __restrict__ Cv, int K, int ldc, int nbx, int cpx)
{
  __shared__ u16 sA[128*64];
  __shared__ u16 sB[128*64];
  int bid = blockIdx.x;
  int s = (bid & 7)*cpx + (bid >> 3);
  gemm_body<OUT_BF>(A, Bt, Cv, K, ldc, s % nbx, s / nbx, sA, sB);
}

// ---------------------------------------------------------------------------
// K4: per-chunk gradient v3. 256 thr / 4 waves; LDS 52.5KB; VGPR target <=128
// (__launch_bounds__(256,4)) -> 3 blocks/CU.
// bufR: kc -> As -> dP (row-major [64][136]) -> dHt ([128][68] view).
// ---------------------------------------------------------------------------
__global__ __launch_bounds__(256,4) void k_grad(const u16* __restrict__ kv,
    const float* __restrict__ lr, const u16* __restrict__ W1t,
    const u16* __restrict__ W2t, const u16* __restrict__ W2s,
    u16* __restrict__ s1, u16* __restrict__ s2)
{
  __shared__ u16 bufR[64*136];   // 8704 u16: [64][136] row-major OR [128][68] dHt
  __shared__ u16 bufAt[128*68];  // Ast [d_h][i]
  __shared__ u16 bufPt[128*68];  // dPt [d_out][i]
  __shared__ float lrs[64];

  const int blk = blockIdx.x;
  const int bhi = blk >> 6, ci = blk & 63;
  const int b = bhi >> 2, hd = bhi & 3;
  const int tid = threadIdx.x;
  const int wv = tid>>6, lane = tid&63, lrow = lane&15, lk = lane>>4;
  int col[2]; col[0] = wv*32 + lrow; col[1] = wv*32 + 16 + lrow;
  const size_t rowbase = (size_t)b*4096 + (size_t)ci*64;
  const u16* kvb = kv + rowbase*1024 + hd*128;

  // ---- stage0: kc rows -> bufR
  #pragma unroll
  for (int rep=0;rep<4;rep++){
    int lin = rep*2048 + tid*8;
    int i = lin >> 7, d = lin & 127;
    *(uint4*)&bufR[i*136 + d] = *(const uint4*)(kvb + (size_t)i*1024 + d);
  }
  if (tid < 64) lrs[tid] = lr[(rowbase + tid)*4 + hd] * (2.0f/128.0f);
  __syncthreads();

  float spv[4][2][4];

  // ---- mm1: H = kc @ W1
  {
    f32x4 acc[4][2] = {};
    #pragma unroll
    for (int k0=0;k0<4;k0++){
      s16x8 w0 = *(const s16x8*)(W1t + col[0]*128 + k0*32 + lk*8);
      s16x8 w1 = *(const s16x8*)(W1t + col[1]*128 + k0*32 + lk*8);
      #pragma unroll
      for (int m=0;m<4;m++){
        s16x8 a = *(const s16x8*)&bufR[(m*16+lrow)*136 + k0*32 + lk*8];
        acc[m][0] = MFMA16(a, w0, acc[m][0]);
        acc[m][1] = MFMA16(a, w1, acc[m][1]);
      }
    }
    __syncthreads();   // kc reads complete
    #pragma unroll
    for (int m=0;m<4;m++)
      #pragma unroll
      for (int n=0;n<2;n++){
        int row0 = m*16 + lk*4;
        u16 av4[4];
        #pragma unroll
        for (int r=0;r<4;r++){
          float h = acc[m][n][r];
          float sg = sigm(h);
          av4[r] = f2bf(h*sg);
          spv[m][n][r] = sg*(1.0f + h*(1.0f - sg));
          bufR[(row0+r)*136 + col[n]] = av4[r];
        }
        *(uint2*)&bufAt[col[n]*68 + row0] = make_uint2(
          (u32)av4[0] | ((u32)av4[1]<<16), (u32)av4[2] | ((u32)av4[3]<<16));
      }
  }
  __syncthreads();

  // ---- mm2: P = A @ W2 ; dP = lr*(P - v)
  {
    f32x4 acc[4][2] = {};
    #pragma unroll
    for (int k0=0;k0<4;k0++){
      s16x8 w0 = *(const s16x8*)(W2t + col[0]*128 + k0*32 + lk*8);
      s16x8 w1 = *(const s16x8*)(W2t + col[1]*128 + k0*32 + lk*8);
      #pragma unroll
      for (int m=0;m<4;m++){
        s16x8 a = *(const s16x8*)&bufR[(m*16+lrow)*136 + k0*32 + lk*8];
        acc[m][0] = MFMA16(a, w0, acc[m][0]);
        acc[m][1] = MFMA16(a, w1, acc[m][1]);
      }
    }
    // v loads (L2-hot, issued together)
    u16 vv[4][2][4];
    #pragma unroll
    for (int m=0;m<4;m++)
      #pragma unroll
      for (int n=0;n<2;n++)
        #pragma unroll
        for (int r=0;r<4;r++)
          vv[m][n][r] = kvb[(size_t)(m*16+lk*4+r)*1024 + 512 + col[n]];
    __syncthreads();   // As reads complete
    #pragma unroll
    for (int m=0;m<4;m++)
      #pragma unroll
      for (int n=0;n<2;n++){
        int row0 = m*16 + lk*4;
        u16 dp4[4];
        #pragma unroll
        for (int r=0;r<4;r++){
          float dp = lrs[row0+r]*(acc[m][n][r] - bf2f(vv[m][n][r]));
          dp4[r] = f2bf(dp);
          bufR[(row0+r)*136 + col[n]] = dp4[r];
        }
        *(uint2*)&bufPt[col[n]*68 + row0] = make_uint2(
          (u32)dp4[0] | ((u32)dp4[1]<<16), (u32)dp4[2] | ((u32)dp4[3]<<16));
      }
  }
  __syncthreads();

  // ---- mm3: dA = dP @ W2^T
  {
    f32x4 da[4][2] = {};
    #pragma unroll
    for (int k0=0;k0<4;k0++){
      s16x8 w0 = *(const s16x8*)(W2s + col[0]*128 + k0*32 + lk*8);
      s16x8 w1 = *(const s16x8*)(W2s + col[1]*128 + k0*32 + lk*8);
      #pragma unroll
      for (int m=0;m<4;m++){
        s16x8 a = *(const s16x8*)&bufR[(m*16+lrow)*136 + k0*32 + lk*8];
        da[m][0] = MFMA16(a, w0, da[m][0]);
        da[m][1] = MFMA16(a, w1, da[m][1]);
      }
    }
    __syncthreads();   // dP reads complete; bufR free
    // dHt = spv*dA -> bufR viewed as [128][68]; spv & da die here
    #pragma unroll
    for (int m=0;m<4;m++)
      #pragma unroll
      for (int n=0;n<2;n++){
        int row0 = m*16 + lk*4;
        u16 dh4[4];
        #pragma unroll
        for (int r=0;r<4;r++) dh4[r] = f2bf(spv[m][n][r]*da[m][n][r]);
        *(uint2*)&bufR[col[n]*68 + row0] = make_uint2(
          (u32)dh4[0] | ((u32)dh4[1]<<16), (u32)dh4[2] | ((u32)dh4[3]<<16));
      }
  }

  const size_t outbase = (size_t)blk * 16384;

  // ---- mm4: s2t[d_out][d_h] = -(dPt x Ast); kct gather issued alongside
  s16x8 kbf[2][2];
  #pragma unroll
  for (int n=0;n<2;n++)
    #pragma unroll
    for (int k0=0;k0<2;k0++)
      #pragma unroll
      for (int j=0;j<8;j++)
        ((u16*)&kbf[n][k0])[j] = kvb[(size_t)(k0*32 + lk*8 + j)*1024 + col[n]];
  {
    f32x4 acc[8][2] = {};
    #pragma unroll
    for (int k0=0;k0<2;k0++){
      s16x8 bf0 = *(const s16x8*)&bufAt[col[0]*68 + k0*32 + lk*8];
      s16x8 bf1 = *(const s16x8*)&bufAt[col[1]*68 + k0*32 + lk*8];
      #pragma unroll
      for (int m=0;m<8;m++){
        s16x8 a = *(const s16x8*)&bufPt[(m*16+lrow)*68 + k0*32 + lk*8];
        acc[m][0] = MFMA16(a, bf0, acc[m][0]);
        acc[m][1] = MFMA16(a, bf1, acc[m][1]);
      }
    }
    #pragma unroll
    for (int m=0;m<8;m++)
      #pragma unroll
      for (int n=0;n<2;n++)
        #pragma unroll
        for (int r=0;r<4;r++)
          s2[outbase + (size_t)(m*16 + lk*4 + r)*128 + col[n]] = f2bf(-acc[m][n][r]);
  }
  __syncthreads();   // dHt writes visible

  // ---- mm5: s1t[d_h][d_in] = -(dHt x kct)
  {
    f32x4 acc[8][2] = {};
    #pragma unroll
    for (int k0=0;k0<2;k0++)
      #pragma unroll
      for (int m=0;m<8;m++){
        s16x8 a = *(const s16x8*)&bufR[(m*16+lrow)*68 + k0*32 + lk*8];
        acc[m][0] = MFMA16(a, kbf[0][k0], acc[m][0]);
        acc[m][1] = MFMA16(a, kbf[1][k0], acc[m][1]);
      }
    #pragma unroll
    for (int m=0;m<8;m++)
      #pragma unroll
      for (int n=0;n<2;n++)
        #pragma unroll
        for (int r=0;r<4;r++)
          s1[outbase + (size_t)(m*16 + lk*4 + r)*128 + col[n]] = f2bf(-acc[m][n][r]);
  }
}

// ---------------------------------------------------------------------------
// K5: fused momentum + decay scans.
// ---------------------------------------------------------------------------
__global__ __launch_bounds__(256) void k_scan(const float* __restrict__ momv,
    const float* __restrict__ dgv, const float* __restrict__ MW1,
    const float* __restrict__ MW2, u16* __restrict__ s1w, u16* __restrict__ s2w)
{
  int bhi = blockIdx.x >> 6, eb = blockIdx.x & 63;
  int e = eb*256 + threadIdx.x;
  float u1 = MW1[(e&127)*128 + (e>>7)];
  float u2 = MW2[(e&127)*128 + (e>>7)];
  float m1 = 0.f, m2 = 0.f;
  size_t base = (size_t)bhi*64*16384 + e;
  #pragma unroll 4
  for (int t=0; t<64; t++){
    float g  = momv[bhi*64 + t];
    float dg = dgv[bhi*64 + t];
    size_t idx = base + (size_t)t*16384;
    float g1v = bf2f(s1w[idx]);
    float g2v = bf2f(s2w[idx]);
    s1w[idx] = f2bf(u1);
    s2w[idx] = f2bf(u2);
    m1 = g*m1 + g1v;
    m2 = g*m2 + g2v;
    u1 = dg*u1 + m1;
    u2 = dg*u2 + m2;
  }
}

// ---------------------------------------------------------------------------
// K6: retrieval (unchanged).
// ---------------------------------------------------------------------------
__global__ __launch_bounds__(512) void k_retr(const u16* __restrict__ qin,
    const u16* __restrict__ w1c, const u16* __restrict__ w2c,
    const float* __restrict__ gate, const float* __restrict__ gamma,
    u16* __restrict__ outp)
{
  __shared__ u16 bufA[64*132];
  __shared__ float rsum[8][64];
  const int blk = blockIdx.x;
  const int bhi = blk >> 6, ci = blk & 63;
  const int b = bhi >> 2, hd = bhi & 3;
  const int tid = threadIdx.x;
  const int wv = tid>>6, lane = tid&63, lrow = lane&15, lk = lane>>4;
  const int nb = wv*16;
  const int colw = nb + lrow;
  const size_t rowbase = (size_t)b*4096 + (size_t)ci*64;
  const u16* w1 = w1c + (size_t)blk*16384;
  const u16* w2 = w2c + (size_t)blk*16384;

  {
    s16x8 wf[4];
    #pragma unroll
    for (int k0=0;k0<4;k0++) wf[k0] = *(const s16x8*)(w1 + colw*128 + k0*32 + lk*8);
    f32x4 acc[4] = {};
    #pragma unroll
    for (int k0=0;k0<4;k0++){
      #pragma unroll
      for (int m=0;m<4;m++){
        s16x8 a = *(const s16x8*)(qin + (rowbase + m*16+lrow)*512 + hd*128 + k0*32 + lk*8);
        acc[m] = MFMA16(a, wf[k0], acc[m]);
      }
    }
    #pragma unroll
    for (int m=0;m<4;m++){
      #pragma unroll
      for (int r=0;r<4;r++){
        float h = acc[m][r];
        bufA[(m*16+lk*4+r)*132 + colw] = f2bf(h*sigm(h));
      }
    }
  }
  __syncthreads();

  f32x4 acc[4] = {};
  {
    s16x8 wf[4];
    #pragma unroll
    for (int k0=0;k0<4;k0++) wf[k0] = *(const s16x8*)(w2 + colw*128 + k0*32 + lk*8);
    #pragma unroll
    for (int k0=0;k0<4;k0++){
      #pragma unroll
      for (int m=0;m<4;m++){
        s16x8 a = *(const s16x8*)&bufA[(m*16+lrow)*132 + k0*32 + lk*8];
        acc[m] = MFMA16(a, wf[k0], acc[m]);
      }
    }
  }
  #pragma unroll
  for (int m=0;m<4;m++){
    #pragma unroll
    for (int r=0;r<4;r++){
      float p = acc[m][r]*acc[m][r];
      p += __shfl_xor(p, 1, 64);
      p += __shfl_xor(p, 2, 64);
      p += __shfl_xor(p, 4, 64);
      p += __shfl_xor(p, 8, 64);
      if (lrow == 0) rsum[wv][m*16 + lk*4 + r] = p;
    }
  }
  __syncthreads();
  float gm = gamma[hd*128 + colw] + 1.0f;
  #pragma unroll
  for (int m=0;m<4;m++){
    #pragma unroll
    for (int r=0;r<4;r++){
      int row = m*16 + lk*4 + r;
      float sum = rsum[0][row]+rsum[1][row]+rsum[2][row]+rsum[3][row]
                + rsum[4][row]+rsum[5][row]+rsum[6][row]+rsum[7][row];
      float inv = rsqrtf(sum*(1.0f/128.0f) + 1e-6f);
      float gt = gate[(rowbase+row)*4 + hd];
      outp[(rowbase+row)*512 + hd*128 + colw] = f2bf(acc[m][r]*inv*gm*gt);
    }
  }
}

// ---------------------------------------------------------------------------
extern "C" void kernel_launch(void* const* d_in, const int* in_sizes, int n_in,
                              void* d_out, int out_size, void* d_ws, size_t ws_size,
                              hipStream_t stream)
{
  const float* seq    = (const float*)d_in[0];
  const float* gstore = (const float*)d_in[1];
  const float* gret   = (const float*)d_in[2];
  const float* W_q    = (const float*)d_in[3];
  const float* W_kv   = (const float*)d_in[4];
  const float* W_step = (const float*)d_in[5];
  const float* W_mom  = (const float*)d_in[6];
  const float* W_dec  = (const float*)d_in[7];
  const float* W_gate = (const float*)d_in[8];
  const float* gamma  = (const float*)d_in[9];
  const float* W_o    = (const float*)d_in[10];
  const float* MW1    = (const float*)d_in[11];
  const float* MW2    = (const float*)d_in[12];
  float* out = (float*)d_out;

  const size_t NS = (size_t)16384*512;
  const size_t NG = (size_t)16*64*16384;
  size_t need = (5*NS + 2*NG + 524288 + 262144 + 262144 + 3*16384)*2
              + (2*65536 + 2048)*4;
  if (ws_size < need) return;

  char* ws = (char*)d_ws;
  u16* s_bf = (u16*)ws; ws += NS*2;        // s; reused as outp
  u16* r_bf = (u16*)ws; ws += NS*2;
  u16* kv_bf= (u16*)ws; ws += 2*NS*2;
  u16* q_bf = (u16*)ws; ws += NS*2;
  u16* s1   = (u16*)ws; ws += NG*2;        // -> w1c after k_scan
  u16* s2   = (u16*)ws; ws += NG*2;        // -> w2c
  u16* Wkvt = (u16*)ws; ws += (size_t)524288*2;
  u16* Wqt  = (u16*)ws; ws += (size_t)262144*2;
  u16* Wot  = (u16*)ws; ws += (size_t)262144*2;
  u16* W1tb = (u16*)ws; ws += (size_t)16384*2;
  u16* W2tb = (u16*)ws; ws += (size_t)16384*2;
  u16* W2sb = (u16*)ws; ws += (size_t)16384*2;
  float* lr   = (float*)ws; ws += (size_t)65536*4;
  float* gatep= (float*)ws; ws += (size_t)65536*4;
  float* momv = (float*)ws; ws += 1024*4;
  float* dgv  = (float*)ws; ws += 1024*4;
  u16* outp = s_bf;

  k_prep<<<272, 256, 0, stream>>>(W_kv, W_q, W_o, MW1, MW2, Wkvt, Wqt, Wot, W1tb, W2tb, W2sb);
  k_tokchunk<<<256, 512, 0, stream>>>(seq, gstore, gret, W_step, W_gate, W_dec, W_mom,
                                      s_bf, r_bf, lr, gatep, momv, dgv);
  k_gemmAB<<<1536, 256, 0, stream>>>(s_bf, Wkvt, kv_bf, r_bf, Wqt, q_bf);
  k_grad<<<1024, 256, 0, stream>>>(kv_bf, lr, W1tb, W2tb, W2sb, s1, s2);
  k_scan<<<1024, 256, 0, stream>>>(momv, dgv, MW1, MW2, s1, s2);
  k_retr<<<1024, 512, 0, stream>>>(q_bf, s1, s2, gatep, gamma, outp);
  k_gemm1<false><<<512, 256, 0, stream>>>(outp, Wot, out, 512, 512, 4, 64);
}

// Round 8
// 173.531 us; speedup vs baseline: 1.3541x; 1.0054x over previous
//
#include <hip/hip_runtime.h>

typedef unsigned short u16;
typedef unsigned int u32;
typedef __attribute__((ext_vector_type(8))) short s16x8;
typedef __attribute__((ext_vector_type(4))) float f32x4;

#define DEV __device__ __forceinline__
#define MFMA16(a,b,c) __builtin_amdgcn_mfma_f32_16x16x32_bf16(a,b,c,0,0,0)

DEV float bf2f(u16 x){ u32 u=((u32)x)<<16; float f; __builtin_memcpy(&f,&u,4); return f; }
DEV u16 f2bf(float f){ u32 u; __builtin_memcpy(&u,&f,4); u32 r=u+0x7FFFu+((u>>16)&1u); return (u16)(r>>16); }
DEV uint4 pack8(const float* f){
  uint4 v;
  v.x=(u32)f2bf(f[0])|((u32)f2bf(f[1])<<16);
  v.y=(u32)f2bf(f[2])|((u32)f2bf(f[3])<<16);
  v.z=(u32)f2bf(f[4])|((u32)f2bf(f[5])<<16);
  v.w=(u32)f2bf(f[6])|((u32)f2bf(f[7])<<16);
  return v;
}
DEV float sigm(float x){ return 1.0f/(1.0f+__expf(-x)); }

// ---------------------------------------------------------------------------
// act-guarded transpose tile: dst[n][k] = bf16(src[k][n]), 64x64, 256 active thr
// ---------------------------------------------------------------------------
DEV void trans_tile_a(const float* src, u16* dst, int K, int Nn, int bx, int by,
                      int tid, bool act, float* ld /* stride 65 */)
{
  int n0 = bx*64, k0 = by*64;
  if (act){
    #pragma unroll
    for (int rr=0; rr<4; rr++){
      int kk = rr*16 + (tid>>4);
      int nn = (tid&15)*4;
      float4 v = *(const float4*)(src + (size_t)(k0+kk)*Nn + n0 + nn);
      ld[kk*65+nn]=v.x; ld[kk*65+nn+1]=v.y; ld[kk*65+nn+2]=v.z; ld[kk*65+nn+3]=v.w;
    }
  }
  __syncthreads();
  if (act){
    int nn2 = tid>>2, kb = (tid&3)*16;
    float o[16];
    #pragma unroll
    for (int j=0;j<16;j++) o[j] = ld[(kb+j)*65+nn2];
    u16* dp = dst + (size_t)(n0+nn2)*K + k0 + kb;
    *(uint4*)dp     = pack8(&o[0]);
    *(uint4*)(dp+8) = pack8(&o[8]);
  }
}

// ---------------------------------------------------------------------------
// K_front: blocks [0,256) = per-token rmsnorm + chunk gates (512 thr);
//          blocks [256,528) = weight prep (256 active thr).
// ---------------------------------------------------------------------------
__global__ __launch_bounds__(512) void k_front(const float* __restrict__ seq,
    const float* __restrict__ gs, const float* __restrict__ gr,
    const float* __restrict__ Wstep, const float* __restrict__ Wgate,
    const float* __restrict__ Wdec, const float* __restrict__ Wmom,
    const float* __restrict__ Wkv, const float* __restrict__ Wq,
    const float* __restrict__ Wo, const float* __restrict__ MW1,
    const float* __restrict__ MW2,
    u16* __restrict__ s, u16* __restrict__ r,
    float* __restrict__ lr, float* __restrict__ gate,
    float* __restrict__ momv, float* __restrict__ dgv,
    u16* __restrict__ Wkvt, u16* __restrict__ Wqt, u16* __restrict__ Wot,
    u16* __restrict__ W1t, u16* __restrict__ W2t, u16* __restrict__ W2s)
{
  __shared__ float smem[8192];   // 32KB: tokchunk pchunk+red; prep transpose tile
  const int blk = blockIdx.x;
  const int tid = threadIdx.x;

  if (blk >= 256){
    int l = blk - 256;
    bool act = tid < 256;
    int t2 = tid & 255;
    if (l < 128)      trans_tile_a(Wkv, Wkvt, 512, 1024, l&15, l>>4, t2, act, smem);
    else if (l < 192){ int m = l-128; trans_tile_a(Wq, Wqt, 512, 512, m&7, m>>3, t2, act, smem); }
    else if (l < 256){ int m = l-192; trans_tile_a(Wo, Wot, 512, 512, m&7, m>>3, t2, act, smem); }
    else if (l < 260){ int m = l-256; trans_tile_a(MW1, W1t, 128, 128, m&1, m>>1, t2, act, smem); }
    else if (l < 264){ int m = l-260; trans_tile_a(MW2, W2t, 128, 128, m&1, m>>1, t2, act, smem); }
    else {
      __syncthreads();           // match barrier count shape (none needed, but harmless)
      if (act){
        int e = ((l-264)*256 + t2)*8;
        float f[8];
        *(float4*)&f[0] = *(const float4*)(MW2+e);
        *(float4*)&f[4] = *(const float4*)(MW2+e+4);
        *(uint4*)(W2s+e) = pack8(f);
      }
    }
    return;
  }

  float* pchunk = smem;          // [8][512]
  float* red    = smem + 4096;   // [8][512]
  const int b = blk >> 6, ci = blk & 63;
  const int wv = tid >> 6, lane = tid & 63;
  const size_t rowbase = (size_t)b*4096 + (size_t)ci*64;

  float psum[8] = {0,0,0,0,0,0,0,0};
  #pragma unroll 1
  for (int tt=0; tt<8; tt++){
    int t = wv*8 + tt;
    const float* row = seq + (rowbase + t)*512;
    float x[8];
    *(float4*)&x[0] = *(const float4*)(row + lane*8);
    *(float4*)&x[4] = *(const float4*)(row + lane*8 + 4);
    float ss = 0.f;
    #pragma unroll
    for (int j=0;j<8;j++) ss += x[j]*x[j];
    #pragma unroll
    for (int o=32;o>=1;o>>=1) ss += __shfl_xor(ss, o, 64);
    float inv = rsqrtf(ss*(1.0f/512.0f) + 1e-6f);
    float al[4] = {0,0,0,0}, ag[4] = {0,0,0,0};
    float sv8[8], rv8[8];
    #pragma unroll
    for (int j=0;j<8;j++){
      int d = lane*8 + j;
      float sn = x[j]*inv;
      float sv = sn*gs[d];
      float rv = sn*gr[d];
      sv8[j]=sv; rv8[j]=rv;
      psum[j] += sv;
      float4 wst = *(const float4*)(Wstep + d*4);
      float4 wgt = *(const float4*)(Wgate + d*4);
      al[0]+=sv*wst.x; al[1]+=sv*wst.y; al[2]+=sv*wst.z; al[3]+=sv*wst.w;
      ag[0]+=rv*wgt.x; ag[1]+=rv*wgt.y; ag[2]+=rv*wgt.z; ag[3]+=rv*wgt.w;
    }
    *(uint4*)(s + (rowbase+t)*512 + lane*8) = pack8(sv8);
    *(uint4*)(r + (rowbase+t)*512 + lane*8) = pack8(rv8);
    #pragma unroll
    for (int o=32;o>=1;o>>=1){
      #pragma unroll
      for (int h=0;h<4;h++){ al[h] += __shfl_xor(al[h], o, 64); ag[h] += __shfl_xor(ag[h], o, 64); }
    }
    if (lane == 0){
      #pragma unroll
      for (int h=0;h<4;h++){
        lr[(rowbase+t)*4 + h]   = sigm(al[h]);
        gate[(rowbase+t)*4 + h] = sigm(ag[h]);
      }
    }
  }
  #pragma unroll
  for (int j=0;j<8;j++) pchunk[wv*512 + lane*8+j] = psum[j];
  __syncthreads();
  {
    int d = tid;
    float mean = 0.f;
    #pragma unroll
    for (int w=0;w<8;w++) mean += pchunk[w*512 + d];
    mean *= (1.0f/64.0f);
    #pragma unroll
    for (int h=0;h<4;h++){
      red[h*512 + d]     = mean*Wdec[d*4+h];
      red[(4+h)*512 + d] = mean*Wmom[d*4+h];
    }
  }
  __syncthreads();
  {
    float sum = 0.f;
    #pragma unroll
    for (int j=0;j<8;j++) sum += red[wv*512 + lane*8+j];
    #pragma unroll
    for (int o=32;o>=1;o>>=1) sum += __shfl_xor(sum, o, 64);
    if (lane == 0){
      if (wv < 4) dgv[((size_t)(b*4+wv))*64 + ci]      = 1.0f - sigm(sum);
      else        momv[((size_t)(b*4+(wv-4)))*64 + ci] = sigm(sum);
    }
  }
}

// ---------------------------------------------------------------------------
// GEMM tile body (m97 structure).
// ---------------------------------------------------------------------------
template<bool OUT_BF>
DEV void gemm_body(const u16* A, const u16* Bt, void* Cv, int K, int ldc,
                   int bx, int by, u16* sA, u16* sB)
{
  const int tid = threadIdx.x;
  const int wv = tid>>6, lane = tid&63, lrow = lane&15, lk = lane>>4;
  const int wm = (wv>>1)*64, wn = (wv&1)*64;
  const int rowbase = by*128, colbase = bx*128;
  const int srow = lane>>3;
  const int scol = (lane&7)*8;
  f32x4 acc[4][4] = {};
  for (int kc = 0; kc < K; kc += 64){
    __syncthreads();
    #pragma unroll
    for (int it=0; it<4; ++it){
      int seg = it*4 + wv;
      int row = seg*8 + srow;
      __builtin_amdgcn_global_load_lds(
        (const __attribute__((address_space(1))) void*)(A + (size_t)(rowbase+row)*K + kc + scol),
        (__attribute__((address_space(3))) void*)&sA[seg*512 + lane*8], 16, 0, 0);
      __builtin_amdgcn_global_load_lds(
        (const __attribute__((address_space(1))) void*)(Bt + (size_t)(colbase+row)*K + kc + scol),
        (__attribute__((address_space(3))) void*)&sB[seg*512 + lane*8], 16, 0, 0);
    }
    __syncthreads();
    #pragma unroll
    for (int k0=0;k0<2;k0++){
      s16x8 a[4], b[4];
      #pragma unroll
      for (int m=0;m<4;m++) a[m] = *(const s16x8*)&sA[(wm+m*16+lrow)*64 + k0*32 + lk*8];
      #pragma unroll
      for (int n=0;n<4;n++) b[n] = *(const s16x8*)&sB[(wn+n*16+lrow)*64 + k0*32 + lk*8];
      #pragma unroll
      for (int m=0;m<4;m++)
        #pragma unroll
        for (int n=0;n<4;n++)
          acc[m][n] = MFMA16(a[m], b[n], acc[m][n]);
    }
  }
  #pragma unroll
  for (int m=0;m<4;m++)
    #pragma unroll
    for (int n=0;n<4;n++)
      #pragma unroll
      for (int r=0;r<4;r++){
        int row = rowbase + wm + m*16 + lk*4 + r;
        int col = colbase + wn + n*16 + lrow;
        float v = acc[m][n][r];
        if (OUT_BF) ((u16*)Cv)[(size_t)row*ldc + col] = f2bf(v);
        else        ((float*)Cv)[(size_t)row*ldc + col] = v;
      }
}

// merged kv + q GEMM
__global__ __launch_bounds__(256) void k_gemmAB(const u16* __restrict__ A1,
    const u16* __restrict__ B1, u16* __restrict__ C1,
    const u16* __restrict__ A2, const u16* __restrict__ B2, u16* __restrict__ C2)
{
  __shared__ u16 sA[128*64];
  __shared__ u16 sB[128*64];
  int bid = blockIdx.x;
  if (bid < 1024){
    int s = (bid & 7)*128 + (bid >> 3);
    gemm_body<true>(A1, B1, C1, 512, 1024, s & 7, s >> 3, sA, sB);
  } else {
    int l = bid - 1024;
    int s = (l & 7)*64 + (l >> 3);
    gemm_body<true>(A2, B2, C2, 512, 512, s & 3, s >> 2, sA, sB);
  }
}

// single GEMM (out-projection)
template<bool OUT_BF>
__global__ __launch_bounds__(256) void k_gemm1(const u16* __restrict__ A,
    const u16* __restrict__ Bt, void* __restrict__ Cv, int K, int ldc, int nbx, int cpx)
{
  __shared__ u16 sA[128*64];
  __shared__ u16 sB[128*64];
  int bid = blockIdx.x;
  int s = (bid & 7)*cpx + (bid >> 3);
  gemm_body<OUT_BF>(A, Bt, Cv, K, ldc, s % nbx, s / nbx, sA, sB);
}

// ---------------------------------------------------------------------------
// K4: per-chunk gradient (unchanged from r7).
// ---------------------------------------------------------------------------
__global__ __launch_bounds__(256,4) void k_grad(const u16* __restrict__ kv,
    const float* __restrict__ lr, const u16* __restrict__ W1t,
    const u16* __restrict__ W2t, const u16* __restrict__ W2s,
    u16* __restrict__ s1, u16* __restrict__ s2)
{
  __shared__ u16 bufR[64*136];
  __shared__ u16 bufAt[128*68];
  __shared__ u16 bufPt[128*68];
  __shared__ float lrs[64];

  const int blk = blockIdx.x;
  const int bhi = blk >> 6, ci = blk & 63;
  const int b = bhi >> 2, hd = bhi & 3;
  const int tid = threadIdx.x;
  const int wv = tid>>6, lane = tid&63, lrow = lane&15, lk = lane>>4;
  int col[2]; col[0] = wv*32 + lrow; col[1] = wv*32 + 16 + lrow;
  const size_t rowbase = (size_t)b*4096 + (size_t)ci*64;
  const u16* kvb = kv + rowbase*1024 + hd*128;

  #pragma unroll
  for (int rep=0;rep<4;rep++){
    int lin = rep*2048 + tid*8;
    int i = lin >> 7, d = lin & 127;
    *(uint4*)&bufR[i*136 + d] = *(const uint4*)(kvb + (size_t)i*1024 + d);
  }
  if (tid < 64) lrs[tid] = lr[(rowbase + tid)*4 + hd] * (2.0f/128.0f);
  __syncthreads();

  float spv[4][2][4];

  // mm1
  {
    f32x4 acc[4][2] = {};
    #pragma unroll
    for (int k0=0;k0<4;k0++){
      s16x8 w0 = *(const s16x8*)(W1t + col[0]*128 + k0*32 + lk*8);
      s16x8 w1 = *(const s16x8*)(W1t + col[1]*128 + k0*32 + lk*8);
      #pragma unroll
      for (int m=0;m<4;m++){
        s16x8 a = *(const s16x8*)&bufR[(m*16+lrow)*136 + k0*32 + lk*8];
        acc[m][0] = MFMA16(a, w0, acc[m][0]);
        acc[m][1] = MFMA16(a, w1, acc[m][1]);
      }
    }
    __syncthreads();
    #pragma unroll
    for (int m=0;m<4;m++)
      #pragma unroll
      for (int n=0;n<2;n++){
        int row0 = m*16 + lk*4;
        u16 av4[4];
        #pragma unroll
        for (int r=0;r<4;r++){
          float h = acc[m][n][r];
          float sg = sigm(h);
          av4[r] = f2bf(h*sg);
          spv[m][n][r] = sg*(1.0f + h*(1.0f - sg));
          bufR[(row0+r)*136 + col[n]] = av4[r];
        }
        *(uint2*)&bufAt[col[n]*68 + row0] = make_uint2(
          (u32)av4[0] | ((u32)av4[1]<<16), (u32)av4[2] | ((u32)av4[3]<<16));
      }
  }
  __syncthreads();

  // mm2
  {
    f32x4 acc[4][2] = {};
    #pragma unroll
    for (int k0=0;k0<4;k0++){
      s16x8 w0 = *(const s16x8*)(W2t + col[0]*128 + k0*32 + lk*8);
      s16x8 w1 = *(const s16x8*)(W2t + col[1]*128 + k0*32 + lk*8);
      #pragma unroll
      for (int m=0;m<4;m++){
        s16x8 a = *(const s16x8*)&bufR[(m*16+lrow)*136 + k0*32 + lk*8];
        acc[m][0] = MFMA16(a, w0, acc[m][0]);
        acc[m][1] = MFMA16(a, w1, acc[m][1]);
      }
    }
    u16 vv[4][2][4];
    #pragma unroll
    for (int m=0;m<4;m++)
      #pragma unroll
      for (int n=0;n<2;n++)
        #pragma unroll
        for (int r=0;r<4;r++)
          vv[m][n][r] = kvb[(size_t)(m*16+lk*4+r)*1024 + 512 + col[n]];
    __syncthreads();
    #pragma unroll
    for (int m=0;m<4;m++)
      #pragma unroll
      for (int n=0;n<2;n++){
        int row0 = m*16 + lk*4;
        u16 dp4[4];
        #pragma unroll
        for (int r=0;r<4;r++){
          float dp = lrs[row0+r]*(acc[m][n][r] - bf2f(vv[m][n][r]));
          dp4[r] = f2bf(dp);
          bufR[(row0+r)*136 + col[n]] = dp4[r];
        }
        *(uint2*)&bufPt[col[n]*68 + row0] = make_uint2(
          (u32)dp4[0] | ((u32)dp4[1]<<16), (u32)dp4[2] | ((u32)dp4[3]<<16));
      }
  }
  __syncthreads();

  // mm3 + dHt
  {
    f32x4 da[4][2] = {};
    #pragma unroll
    for (int k0=0;k0<4;k0++){
      s16x8 w0 = *(const s16x8*)(W2s + col[0]*128 + k0*32 + lk*8);
      s16x8 w1 = *(const s16x8*)(W2s + col[1]*128 + k0*32 + lk*8);
      #pragma unroll
      for (int m=0;m<4;m++){
        s16x8 a = *(const s16x8*)&bufR[(m*16+lrow)*136 + k0*32 + lk*8];
        da[m][0] = MFMA16(a, w0, da[m][0]);
        da[m][1] = MFMA16(a, w1, da[m][1]);
      }
    }
    __syncthreads();
    #pragma unroll
    for (int m=0;m<4;m++)
      #pragma unroll
      for (int n=0;n<2;n++){
        int row0 = m*16 + lk*4;
        u16 dh4[4];
        #pragma unroll
        for (int r=0;r<4;r++) dh4[r] = f2bf(spv[m][n][r]*da[m][n][r]);
        *(uint2*)&bufR[col[n]*68 + row0] = make_uint2(
          (u32)dh4[0] | ((u32)dh4[1]<<16), (u32)dh4[2] | ((u32)dh4[3]<<16));
      }
  }

  const size_t outbase = (size_t)blk * 16384;

  // mm4 + kct gather
  s16x8 kbf[2][2];
  #pragma unroll
  for (int n=0;n<2;n++)
    #pragma unroll
    for (int k0=0;k0<2;k0++)
      #pragma unroll
      for (int j=0;j<8;j++)
        ((u16*)&kbf[n][k0])[j] = kvb[(size_t)(k0*32 + lk*8 + j)*1024 + col[n]];
  {
    f32x4 acc[8][2] = {};
    #pragma unroll
    for (int k0=0;k0<2;k0++){
      s16x8 bf0 = *(const s16x8*)&bufAt[col[0]*68 + k0*32 + lk*8];
      s16x8 bf1 = *(const s16x8*)&bufAt[col[1]*68 + k0*32 + lk*8];
      #pragma unroll
      for (int m=0;m<8;m++){
        s16x8 a = *(const s16x8*)&bufPt[(m*16+lrow)*68 + k0*32 + lk*8];
        acc[m][0] = MFMA16(a, bf0, acc[m][0]);
        acc[m][1] = MFMA16(a, bf1, acc[m][1]);
      }
    }
    #pragma unroll
    for (int m=0;m<8;m++)
      #pragma unroll
      for (int n=0;n<2;n++)
        #pragma unroll
        for (int r=0;r<4;r++)
          s2[outbase + (size_t)(m*16 + lk*4 + r)*128 + col[n]] = f2bf(-acc[m][n][r]);
  }
  __syncthreads();

  // mm5
  {
    f32x4 acc[8][2] = {};
    #pragma unroll
    for (int k0=0;k0<2;k0++)
      #pragma unroll
      for (int m=0;m<8;m++){
        s16x8 a = *(const s16x8*)&bufR[(m*16+lrow)*68 + k0*32 + lk*8];
        acc[m][0] = MFMA16(a, kbf[0][k0], acc[m][0]);
        acc[m][1] = MFMA16(a, kbf[1][k0], acc[m][1]);
      }
    #pragma unroll
    for (int m=0;m<8;m++)
      #pragma unroll
      for (int n=0;n<2;n++)
        #pragma unroll
        for (int r=0;r<4;r++)
          s1[outbase + (size_t)(m*16 + lk*4 + r)*128 + col[n]] = f2bf(-acc[m][n][r]);
  }
}

// ---------------------------------------------------------------------------
// K5: fused momentum + decay scans, 2 elems/thread (u32 loads), unroll 4.
// ---------------------------------------------------------------------------
__global__ __launch_bounds__(256) void k_scan(const float* __restrict__ momv,
    const float* __restrict__ dgv, const float* __restrict__ MW1,
    const float* __restrict__ MW2, u16* __restrict__ s1w, u16* __restrict__ s2w)
{
  int bhi = blockIdx.x >> 5, eb = blockIdx.x & 31;
  int e0 = eb*512 + threadIdx.x*2;
  float u1a = MW1[(e0&127)*128 + (e0>>7)];
  float u1b = MW1[((e0+1)&127)*128 + ((e0+1)>>7)];
  float u2a = MW2[(e0&127)*128 + (e0>>7)];
  float u2b = MW2[((e0+1)&127)*128 + ((e0+1)>>7)];
  float m1a = 0.f, m1b = 0.f, m2a = 0.f, m2b = 0.f;
  size_t base = (size_t)bhi*64*16384 + e0;
  const float* mv = momv + bhi*64;
  const float* dv = dgv + bhi*64;
  #pragma unroll 4
  for (int t=0; t<64; t++){
    float g  = mv[t];
    float dg = dv[t];
    size_t idx = base + (size_t)t*16384;
    u32 a = *(const u32*)(s1w + idx);
    u32 c = *(const u32*)(s2w + idx);
    *(u32*)(s1w + idx) = (u32)f2bf(u1a) | ((u32)f2bf(u1b)<<16);
    *(u32*)(s2w + idx) = (u32)f2bf(u2a) | ((u32)f2bf(u2b)<<16);
    m1a = g*m1a + bf2f((u16)(a&0xffffu));
    m1b = g*m1b + bf2f((u16)(a>>16));
    m2a = g*m2a + bf2f((u16)(c&0xffffu));
    m2b = g*m2b + bf2f((u16)(c>>16));
    u1a = dg*u1a + m1a;
    u1b = dg*u1b + m1b;
    u2a = dg*u2a + m2a;
    u2b = dg*u2b + m2b;
  }
}

// ---------------------------------------------------------------------------
// K6: retrieval (unchanged).
// ---------------------------------------------------------------------------
__global__ __launch_bounds__(512) void k_retr(const u16* __restrict__ qin,
    const u16* __restrict__ w1c, const u16* __restrict__ w2c,
    const float* __restrict__ gate, const float* __restrict__ gamma,
    u16* __restrict__ outp)
{
  __shared__ u16 bufA[64*132];
  __shared__ float rsum[8][64];
  const int blk = blockIdx.x;
  const int bhi = blk >> 6, ci = blk & 63;
  const int b = bhi >> 2, hd = bhi & 3;
  const int tid = threadIdx.x;
  const int wv = tid>>6, lane = tid&63, lrow = lane&15, lk = lane>>4;
  const int nb = wv*16;
  const int colw = nb + lrow;
  const size_t rowbase = (size_t)b*4096 + (size_t)ci*64;
  const u16* w1 = w1c + (size_t)blk*16384;
  const u16* w2 = w2c + (size_t)blk*16384;

  {
    s16x8 wf[4];
    #pragma unroll
    for (int k0=0;k0<4;k0++) wf[k0] = *(const s16x8*)(w1 + colw*128 + k0*32 + lk*8);
    f32x4 acc[4] = {};
    #pragma unroll
    for (int k0=0;k0<4;k0++){
      #pragma unroll
      for (int m=0;m<4;m++){
        s16x8 a = *(const s16x8*)(qin + (rowbase + m*16+lrow)*512 + hd*128 + k0*32 + lk*8);
        acc[m] = MFMA16(a, wf[k0], acc[m]);
      }
    }
    #pragma unroll
    for (int m=0;m<4;m++){
      #pragma unroll
      for (int r=0;r<4;r++){
        float h = acc[m][r];
        bufA[(m*16+lk*4+r)*132 + colw] = f2bf(h*sigm(h));
      }
    }
  }
  __syncthreads();

  f32x4 acc[4] = {};
  {
    s16x8 wf[4];
    #pragma unroll
    for (int k0=0;k0<4;k0++) wf[k0] = *(const s16x8*)(w2 + colw*128 + k0*32 + lk*8);
    #pragma unroll
    for (int k0=0;k0<4;k0++){
      #pragma unroll
      for (int m=0;m<4;m++){
        s16x8 a = *(const s16x8*)&bufA[(m*16+lrow)*132 + k0*32 + lk*8];
        acc[m] = MFMA16(a, wf[k0], acc[m]);
      }
    }
  }
  #pragma unroll
  for (int m=0;m<4;m++){
    #pragma unroll
    for (int r=0;r<4;r++){
      float p = acc[m][r]*acc[m][r];
      p += __shfl_xor(p, 1, 64);
      p += __shfl_xor(p, 2, 64);
      p += __shfl_xor(p, 4, 64);
      p += __shfl_xor(p, 8, 64);
      if (lrow == 0) rsum[wv][m*16 + lk*4 + r] = p;
    }
  }
  __syncthreads();
  float gm = gamma[hd*128 + colw] + 1.0f;
  #pragma unroll
  for (int m=0;m<4;m++){
    #pragma unroll
    for (int r=0;r<4;r++){
      int row = m*16 + lk*4 + r;
      float sum = rsum[0][row]+rsum[1][row]+rsum[2][row]+rsum[3][row]
                + rsum[4][row]+rsum[5][row]+rsum[6][row]+rsum[7][row];
      float inv = rsqrtf(sum*(1.0f/128.0f) + 1e-6f);
      float gt = gate[(rowbase+row)*4 + hd];
      outp[(rowbase+row)*512 + hd*128 + colw] = f2bf(acc[m][r]*inv*gm*gt);
    }
  }
}

// ---------------------------------------------------------------------------
extern "C" void kernel_launch(void* const* d_in, const int* in_sizes, int n_in,
                              void* d_out, int out_size, void* d_ws, size_t ws_size,
                              hipStream_t stream)
{
  const float* seq    = (const float*)d_in[0];
  const float* gstore = (const float*)d_in[1];
  const float* gret   = (const float*)d_in[2];
  const float* W_q    = (const float*)d_in[3];
  const float* W_kv   = (const float*)d_in[4];
  const float* W_step = (const float*)d_in[5];
  const float* W_mom  = (const float*)d_in[6];
  const float* W_dec  = (const float*)d_in[7];
  const float* W_gate = (const float*)d_in[8];
  const float* gamma  = (const float*)d_in[9];
  const float* W_o    = (const float*)d_in[10];
  const float* MW1    = (const float*)d_in[11];
  const float* MW2    = (const float*)d_in[12];
  float* out = (float*)d_out;

  const size_t NS = (size_t)16384*512;
  const size_t NG = (size_t)16*64*16384;
  size_t need = (5*NS + 2*NG + 524288 + 262144 + 262144 + 3*16384)*2
              + (2*65536 + 2048)*4;
  if (ws_size < need) return;

  char* ws = (char*)d_ws;
  u16* s_bf = (u16*)ws; ws += NS*2;        // s; reused as outp
  u16* r_bf = (u16*)ws; ws += NS*2;
  u16* kv_bf= (u16*)ws; ws += 2*NS*2;
  u16* q_bf = (u16*)ws; ws += NS*2;
  u16* s1   = (u16*)ws; ws += NG*2;        // -> w1c after k_scan
  u16* s2   = (u16*)ws; ws += NG*2;        // -> w2c
  u16* Wkvt = (u16*)ws; ws += (size_t)524288*2;
  u16* Wqt  = (u16*)ws; ws += (size_t)262144*2;
  u16* Wot  = (u16*)ws; ws += (size_t)262144*2;
  u16* W1tb = (u16*)ws; ws += (size_t)16384*2;
  u16* W2tb = (u16*)ws; ws += (size_t)16384*2;
  u16* W2sb = (u16*)ws; ws += (size_t)16384*2;
  float* lr   = (float*)ws; ws += (size_t)65536*4;
  float* gatep= (float*)ws; ws += (size_t)65536*4;
  float* momv = (float*)ws; ws += 1024*4;
  float* dgv  = (float*)ws; ws += 1024*4;
  u16* outp = s_bf;

  k_front<<<528, 512, 0, stream>>>(seq, gstore, gret, W_step, W_gate, W_dec, W_mom,
                                   W_kv, W_q, W_o, MW1, MW2,
                                   s_bf, r_bf, lr, gatep, momv, dgv,
                                   Wkvt, Wqt, Wot, W1tb, W2tb, W2sb);
  k_gemmAB<<<1536, 256, 0, stream>>>(s_bf, Wkvt, kv_bf, r_bf, Wqt, q_bf);
  k_grad<<<1024, 256, 0, stream>>>(kv_bf, lr, W1tb, W2tb, W2sb, s1, s2);
  k_scan<<<512, 256, 0, stream>>>(momv, dgv, MW1, MW2, s1, s2);
  k_retr<<<1024, 512, 0, stream>>>(q_bf, s1, s2, gatep, gamma, outp);
  k_gemm1<false><<<512, 256, 0, stream>>>(outp, Wot, out, 512, 512, 4, 64);
}

// Round 9
// 171.496 us; speedup vs baseline: 1.3702x; 1.0119x over previous
//
#include <hip/hip_runtime.h>

typedef unsigned short u16;
typedef unsigned int u32;
typedef __attribute__((ext_vector_type(8))) short s16x8;
typedef __attribute__((ext_vector_type(4))) float f32x4;

#define DEV __device__ __forceinline__
#define MFMA16(a,b,c) __builtin_amdgcn_mfma_f32_16x16x32_bf16(a,b,c,0,0,0)

DEV float bf2f(u16 x){ u32 u=((u32)x)<<16; float f; __builtin_memcpy(&f,&u,4); return f; }
DEV u16 f2bf(float f){ u32 u; __builtin_memcpy(&u,&f,4); u32 r=u+0x7FFFu+((u>>16)&1u); return (u16)(r>>16); }
DEV uint4 pack8(const float* f){
  uint4 v;
  v.x=(u32)f2bf(f[0])|((u32)f2bf(f[1])<<16);
  v.y=(u32)f2bf(f[2])|((u32)f2bf(f[3])<<16);
  v.z=(u32)f2bf(f[4])|((u32)f2bf(f[5])<<16);
  v.w=(u32)f2bf(f[6])|((u32)f2bf(f[7])<<16);
  return v;
}
DEV float sigm(float x){ return 1.0f/(1.0f+__expf(-x)); }

// Fragment layout for w1c/w2c (and s1/s2): addr(col,k) =
//   (col>>4)*2048 + (k>>5)*512 + ((k>>3)&3)*128 + (col&15)*8 + (k&7)
// Reader (k_retr wave wv, lane l): frag k0 at  wv*2048 + k0*512 + l*8  (coalesced).

// ---------------------------------------------------------------------------
// act-guarded transpose tile: dst[n][k] = bf16(src[k][n]), 64x64, 256 active thr
// ---------------------------------------------------------------------------
DEV void trans_tile_a(const float* src, u16* dst, int K, int Nn, int bx, int by,
                      int tid, bool act, float* ld /* stride 65 */)
{
  int n0 = bx*64, k0 = by*64;
  if (act){
    #pragma unroll
    for (int rr=0; rr<4; rr++){
      int kk = rr*16 + (tid>>4);
      int nn = (tid&15)*4;
      float4 v = *(const float4*)(src + (size_t)(k0+kk)*Nn + n0 + nn);
      ld[kk*65+nn]=v.x; ld[kk*65+nn+1]=v.y; ld[kk*65+nn+2]=v.z; ld[kk*65+nn+3]=v.w;
    }
  }
  __syncthreads();
  if (act){
    int nn2 = tid>>2, kb = (tid&3)*16;
    float o[16];
    #pragma unroll
    for (int j=0;j<16;j++) o[j] = ld[(kb+j)*65+nn2];
    u16* dp = dst + (size_t)(n0+nn2)*K + k0 + kb;
    *(uint4*)dp     = pack8(&o[0]);
    *(uint4*)(dp+8) = pack8(&o[8]);
  }
}

// ---------------------------------------------------------------------------
// K_front: blocks [0,256) = per-token rmsnorm + chunk gates (512 thr);
//          blocks [256,528) = weight prep (256 active thr).
// ---------------------------------------------------------------------------
__global__ __launch_bounds__(512) void k_front(const float* __restrict__ seq,
    const float* __restrict__ gs, const float* __restrict__ gr,
    const float* __restrict__ Wstep, const float* __restrict__ Wgate,
    const float* __restrict__ Wdec, const float* __restrict__ Wmom,
    const float* __restrict__ Wkv, const float* __restrict__ Wq,
    const float* __restrict__ Wo, const float* __restrict__ MW1,
    const float* __restrict__ MW2,
    u16* __restrict__ s, u16* __restrict__ r,
    float* __restrict__ lr, float* __restrict__ gate,
    float* __restrict__ momv, float* __restrict__ dgv,
    u16* __restrict__ Wkvt, u16* __restrict__ Wqt, u16* __restrict__ Wot,
    u16* __restrict__ W1t, u16* __restrict__ W2t, u16* __restrict__ W2s)
{
  __shared__ float smem[8192];
  const int blk = blockIdx.x;
  const int tid = threadIdx.x;

  if (blk >= 256){
    int l = blk - 256;
    bool act = tid < 256;
    int t2 = tid & 255;
    if (l < 128)      trans_tile_a(Wkv, Wkvt, 512, 1024, l&15, l>>4, t2, act, smem);
    else if (l < 192){ int m = l-128; trans_tile_a(Wq, Wqt, 512, 512, m&7, m>>3, t2, act, smem); }
    else if (l < 256){ int m = l-192; trans_tile_a(Wo, Wot, 512, 512, m&7, m>>3, t2, act, smem); }
    else if (l < 260){ int m = l-256; trans_tile_a(MW1, W1t, 128, 128, m&1, m>>1, t2, act, smem); }
    else if (l < 264){ int m = l-260; trans_tile_a(MW2, W2t, 128, 128, m&1, m>>1, t2, act, smem); }
    else {
      __syncthreads();
      if (act){
        int e = ((l-264)*256 + t2)*8;
        float f[8];
        *(float4*)&f[0] = *(const float4*)(MW2+e);
        *(float4*)&f[4] = *(const float4*)(MW2+e+4);
        *(uint4*)(W2s+e) = pack8(f);
      }
    }
    return;
  }

  float* pchunk = smem;
  float* red    = smem + 4096;
  const int b = blk >> 6, ci = blk & 63;
  const int wv = tid >> 6, lane = tid & 63;
  const size_t rowbase = (size_t)b*4096 + (size_t)ci*64;

  float psum[8] = {0,0,0,0,0,0,0,0};
  #pragma unroll 1
  for (int tt=0; tt<8; tt++){
    int t = wv*8 + tt;
    const float* row = seq + (rowbase + t)*512;
    float x[8];
    *(float4*)&x[0] = *(const float4*)(row + lane*8);
    *(float4*)&x[4] = *(const float4*)(row + lane*8 + 4);
    float ss = 0.f;
    #pragma unroll
    for (int j=0;j<8;j++) ss += x[j]*x[j];
    #pragma unroll
    for (int o=32;o>=1;o>>=1) ss += __shfl_xor(ss, o, 64);
    float inv = rsqrtf(ss*(1.0f/512.0f) + 1e-6f);
    float al[4] = {0,0,0,0}, ag[4] = {0,0,0,0};
    float sv8[8], rv8[8];
    #pragma unroll
    for (int j=0;j<8;j++){
      int d = lane*8 + j;
      float sn = x[j]*inv;
      float sv = sn*gs[d];
      float rv = sn*gr[d];
      sv8[j]=sv; rv8[j]=rv;
      psum[j] += sv;
      float4 wst = *(const float4*)(Wstep + d*4);
      float4 wgt = *(const float4*)(Wgate + d*4);
      al[0]+=sv*wst.x; al[1]+=sv*wst.y; al[2]+=sv*wst.z; al[3]+=sv*wst.w;
      ag[0]+=rv*wgt.x; ag[1]+=rv*wgt.y; ag[2]+=rv*wgt.z; ag[3]+=rv*wgt.w;
    }
    *(uint4*)(s + (rowbase+t)*512 + lane*8) = pack8(sv8);
    *(uint4*)(r + (rowbase+t)*512 + lane*8) = pack8(rv8);
    #pragma unroll
    for (int o=32;o>=1;o>>=1){
      #pragma unroll
      for (int h=0;h<4;h++){ al[h] += __shfl_xor(al[h], o, 64); ag[h] += __shfl_xor(ag[h], o, 64); }
    }
    if (lane == 0){
      #pragma unroll
      for (int h=0;h<4;h++){
        lr[(rowbase+t)*4 + h]   = sigm(al[h]);
        gate[(rowbase+t)*4 + h] = sigm(ag[h]);
      }
    }
  }
  #pragma unroll
  for (int j=0;j<8;j++) pchunk[wv*512 + lane*8+j] = psum[j];
  __syncthreads();
  {
    int d = tid;
    float mean = 0.f;
    #pragma unroll
    for (int w=0;w<8;w++) mean += pchunk[w*512 + d];
    mean *= (1.0f/64.0f);
    #pragma unroll
    for (int h=0;h<4;h++){
      red[h*512 + d]     = mean*Wdec[d*4+h];
      red[(4+h)*512 + d] = mean*Wmom[d*4+h];
    }
  }
  __syncthreads();
  {
    float sum = 0.f;
    #pragma unroll
    for (int j=0;j<8;j++) sum += red[wv*512 + lane*8+j];
    #pragma unroll
    for (int o=32;o>=1;o>>=1) sum += __shfl_xor(sum, o, 64);
    if (lane == 0){
      if (wv < 4) dgv[((size_t)(b*4+wv))*64 + ci]      = 1.0f - sigm(sum);
      else        momv[((size_t)(b*4+(wv-4)))*64 + ci] = sigm(sum);
    }
  }
}

// ---------------------------------------------------------------------------
// GEMM tile body (m97 structure).
// ---------------------------------------------------------------------------
template<bool OUT_BF>
DEV void gemm_body(const u16* A, const u16* Bt, void* Cv, int K, int ldc,
                   int bx, int by, u16* sA, u16* sB)
{
  const int tid = threadIdx.x;
  const int wv = tid>>6, lane = tid&63, lrow = lane&15, lk = lane>>4;
  const int wm = (wv>>1)*64, wn = (wv&1)*64;
  const int rowbase = by*128, colbase = bx*128;
  const int srow = lane>>3;
  const int scol = (lane&7)*8;
  f32x4 acc[4][4] = {};
  for (int kc = 0; kc < K; kc += 64){
    __syncthreads();
    #pragma unroll
    for (int it=0; it<4; ++it){
      int seg = it*4 + wv;
      int row = seg*8 + srow;
      __builtin_amdgcn_global_load_lds(
        (const __attribute__((address_space(1))) void*)(A + (size_t)(rowbase+row)*K + kc + scol),
        (__attribute__((address_space(3))) void*)&sA[seg*512 + lane*8], 16, 0, 0);
      __builtin_amdgcn_global_load_lds(
        (const __attribute__((address_space(1))) void*)(Bt + (size_t)(colbase+row)*K + kc + scol),
        (__attribute__((address_space(3))) void*)&sB[seg*512 + lane*8], 16, 0, 0);
    }
    __syncthreads();
    #pragma unroll
    for (int k0=0;k0<2;k0++){
      s16x8 a[4], b[4];
      #pragma unroll
      for (int m=0;m<4;m++) a[m] = *(const s16x8*)&sA[(wm+m*16+lrow)*64 + k0*32 + lk*8];
      #pragma unroll
      for (int n=0;n<4;n++) b[n] = *(const s16x8*)&sB[(wn+n*16+lrow)*64 + k0*32 + lk*8];
      #pragma unroll
      for (int m=0;m<4;m++)
        #pragma unroll
        for (int n=0;n<4;n++)
          acc[m][n] = MFMA16(a[m], b[n], acc[m][n]);
    }
  }
  #pragma unroll
  for (int m=0;m<4;m++)
    #pragma unroll
    for (int n=0;n<4;n++)
      #pragma unroll
      for (int r=0;r<4;r++){
        int row = rowbase + wm + m*16 + lk*4 + r;
        int col = colbase + wn + n*16 + lrow;
        float v = acc[m][n][r];
        if (OUT_BF) ((u16*)Cv)[(size_t)row*ldc + col] = f2bf(v);
        else        ((float*)Cv)[(size_t)row*ldc + col] = v;
      }
}

// merged kv + q GEMM
__global__ __launch_bounds__(256) void k_gemmAB(const u16* __restrict__ A1,
    const u16* __restrict__ B1, u16* __restrict__ C1,
    const u16* __restrict__ A2, const u16* __restrict__ B2, u16* __restrict__ C2)
{
  __shared__ u16 sA[128*64];
  __shared__ u16 sB[128*64];
  int bid = blockIdx.x;
  if (bid < 1024){
    int s = (bid & 7)*128 + (bid >> 3);
    gemm_body<true>(A1, B1, C1, 512, 1024, s & 7, s >> 3, sA, sB);
  } else {
    int l = bid - 1024;
    int s = (l & 7)*64 + (l >> 3);
    gemm_body<true>(A2, B2, C2, 512, 512, s & 3, s >> 2, sA, sB);
  }
}

// single GEMM (out-projection)
template<bool OUT_BF>
__global__ __launch_bounds__(256) void k_gemm1(const u16* __restrict__ A,
    const u16* __restrict__ Bt, void* __restrict__ Cv, int K, int ldc, int nbx, int cpx)
{
  __shared__ u16 sA[128*64];
  __shared__ u16 sB[128*64];
  int bid = blockIdx.x;
  int s = (bid & 7)*cpx + (bid >> 3);
  gemm_body<OUT_BF>(A, Bt, Cv, K, ldc, s % nbx, s / nbx, sA, sB);
}

// ---------------------------------------------------------------------------
// K4: per-chunk gradient. s1/s2 written in fragment layout F.
// ---------------------------------------------------------------------------
__global__ __launch_bounds__(256,4) void k_grad(const u16* __restrict__ kv,
    const float* __restrict__ lr, const u16* __restrict__ W1t,
    const u16* __restrict__ W2t, const u16* __restrict__ W2s,
    u16* __restrict__ s1, u16* __restrict__ s2)
{
  __shared__ u16 bufR[64*136];
  __shared__ u16 bufAt[128*68];
  __shared__ u16 bufPt[128*68];
  __shared__ float lrs[64];

  const int blk = blockIdx.x;
  const int bhi = blk >> 6, ci = blk & 63;
  const int b = bhi >> 2, hd = bhi & 3;
  const int tid = threadIdx.x;
  const int wv = tid>>6, lane = tid&63, lrow = lane&15, lk = lane>>4;
  int col[2]; col[0] = wv*32 + lrow; col[1] = wv*32 + 16 + lrow;
  // fragment-layout constants: addr = m*2048 + wv*512 + f_hi[n] + (lk*4+r)*8 + f_lo[n]
  const int f_hi[2] = { (lrow>>3)*128, ((16+lrow)>>3)*128 };
  const int f_lo[2] = { lrow&7, (16+lrow)&7 };
  const int fbase = wv*512;
  const size_t rowbase = (size_t)b*4096 + (size_t)ci*64;
  const u16* kvb = kv + rowbase*1024 + hd*128;

  #pragma unroll
  for (int rep=0;rep<4;rep++){
    int lin = rep*2048 + tid*8;
    int i = lin >> 7, d = lin & 127;
    *(uint4*)&bufR[i*136 + d] = *(const uint4*)(kvb + (size_t)i*1024 + d);
  }
  if (tid < 64) lrs[tid] = lr[(rowbase + tid)*4 + hd] * (2.0f/128.0f);
  __syncthreads();

  float spv[4][2][4];

  // mm1
  {
    f32x4 acc[4][2] = {};
    #pragma unroll
    for (int k0=0;k0<4;k0++){
      s16x8 w0 = *(const s16x8*)(W1t + col[0]*128 + k0*32 + lk*8);
      s16x8 w1 = *(const s16x8*)(W1t + col[1]*128 + k0*32 + lk*8);
      #pragma unroll
      for (int m=0;m<4;m++){
        s16x8 a = *(const s16x8*)&bufR[(m*16+lrow)*136 + k0*32 + lk*8];
        acc[m][0] = MFMA16(a, w0, acc[m][0]);
        acc[m][1] = MFMA16(a, w1, acc[m][1]);
      }
    }
    __syncthreads();
    #pragma unroll
    for (int m=0;m<4;m++)
      #pragma unroll
      for (int n=0;n<2;n++){
        int row0 = m*16 + lk*4;
        u16 av4[4];
        #pragma unroll
        for (int r=0;r<4;r++){
          float h = acc[m][n][r];
          float sg = sigm(h);
          av4[r] = f2bf(h*sg);
          spv[m][n][r] = sg*(1.0f + h*(1.0f - sg));
          bufR[(row0+r)*136 + col[n]] = av4[r];
        }
        *(uint2*)&bufAt[col[n]*68 + row0] = make_uint2(
          (u32)av4[0] | ((u32)av4[1]<<16), (u32)av4[2] | ((u32)av4[3]<<16));
      }
  }
  __syncthreads();

  // mm2
  {
    f32x4 acc[4][2] = {};
    #pragma unroll
    for (int k0=0;k0<4;k0++){
      s16x8 w0 = *(const s16x8*)(W2t + col[0]*128 + k0*32 + lk*8);
      s16x8 w1 = *(const s16x8*)(W2t + col[1]*128 + k0*32 + lk*8);
      #pragma unroll
      for (int m=0;m<4;m++){
        s16x8 a = *(const s16x8*)&bufR[(m*16+lrow)*136 + k0*32 + lk*8];
        acc[m][0] = MFMA16(a, w0, acc[m][0]);
        acc[m][1] = MFMA16(a, w1, acc[m][1]);
      }
    }
    u16 vv[4][2][4];
    #pragma unroll
    for (int m=0;m<4;m++)
      #pragma unroll
      for (int n=0;n<2;n++)
        #pragma unroll
        for (int r=0;r<4;r++)
          vv[m][n][r] = kvb[(size_t)(m*16+lk*4+r)*1024 + 512 + col[n]];
    __syncthreads();
    #pragma unroll
    for (int m=0;m<4;m++)
      #pragma unroll
      for (int n=0;n<2;n++){
        int row0 = m*16 + lk*4;
        u16 dp4[4];
        #pragma unroll
        for (int r=0;r<4;r++){
          float dp = lrs[row0+r]*(acc[m][n][r] - bf2f(vv[m][n][r]));
          dp4[r] = f2bf(dp);
          bufR[(row0+r)*136 + col[n]] = dp4[r];
        }
        *(uint2*)&bufPt[col[n]*68 + row0] = make_uint2(
          (u32)dp4[0] | ((u32)dp4[1]<<16), (u32)dp4[2] | ((u32)dp4[3]<<16));
      }
  }
  __syncthreads();

  // mm3 + dHt
  {
    f32x4 da[4][2] = {};
    #pragma unroll
    for (int k0=0;k0<4;k0++){
      s16x8 w0 = *(const s16x8*)(W2s + col[0]*128 + k0*32 + lk*8);
      s16x8 w1 = *(const s16x8*)(W2s + col[1]*128 + k0*32 + lk*8);
      #pragma unroll
      for (int m=0;m<4;m++){
        s16x8 a = *(const s16x8*)&bufR[(m*16+lrow)*136 + k0*32 + lk*8];
        da[m][0] = MFMA16(a, w0, da[m][0]);
        da[m][1] = MFMA16(a, w1, da[m][1]);
      }
    }
    __syncthreads();
    #pragma unroll
    for (int m=0;m<4;m++)
      #pragma unroll
      for (int n=0;n<2;n++){
        int row0 = m*16 + lk*4;
        u16 dh4[4];
        #pragma unroll
        for (int r=0;r<4;r++) dh4[r] = f2bf(spv[m][n][r]*da[m][n][r]);
        *(uint2*)&bufR[col[n]*68 + row0] = make_uint2(
          (u32)dh4[0] | ((u32)dh4[1]<<16), (u32)dh4[2] | ((u32)dh4[3]<<16));
      }
  }

  const size_t outbase = (size_t)blk * 16384;

  // mm4 (s2 in fragment layout) + kct gather
  s16x8 kbf[2][2];
  #pragma unroll
  for (int n=0;n<2;n++)
    #pragma unroll
    for (int k0=0;k0<2;k0++)
      #pragma unroll
      for (int j=0;j<8;j++)
        ((u16*)&kbf[n][k0])[j] = kvb[(size_t)(k0*32 + lk*8 + j)*1024 + col[n]];
  {
    f32x4 acc[8][2] = {};
    #pragma unroll
    for (int k0=0;k0<2;k0++){
      s16x8 bf0 = *(const s16x8*)&bufAt[col[0]*68 + k0*32 + lk*8];
      s16x8 bf1 = *(const s16x8*)&bufAt[col[1]*68 + k0*32 + lk*8];
      #pragma unroll
      for (int m=0;m<8;m++){
        s16x8 a = *(const s16x8*)&bufPt[(m*16+lrow)*68 + k0*32 + lk*8];
        acc[m][0] = MFMA16(a, bf0, acc[m][0]);
        acc[m][1] = MFMA16(a, bf1, acc[m][1]);
      }
    }
    #pragma unroll
    for (int m=0;m<8;m++)
      #pragma unroll
      for (int n=0;n<2;n++)
        #pragma unroll
        for (int r=0;r<4;r++)
          s2[outbase + m*2048 + fbase + f_hi[n] + (lk*4+r)*8 + f_lo[n]] = f2bf(-acc[m][n][r]);
  }
  __syncthreads();

  // mm5 (s1 in fragment layout)
  {
    f32x4 acc[8][2] = {};
    #pragma unroll
    for (int k0=0;k0<2;k0++)
      #pragma unroll
      for (int m=0;m<8;m++){
        s16x8 a = *(const s16x8*)&bufR[(m*16+lrow)*68 + k0*32 + lk*8];
        acc[m][0] = MFMA16(a, kbf[0][k0], acc[m][0]);
        acc[m][1] = MFMA16(a, kbf[1][k0], acc[m][1]);
      }
    #pragma unroll
    for (int m=0;m<8;m++)
      #pragma unroll
      for (int n=0;n<2;n++)
        #pragma unroll
        for (int r=0;r<4;r++)
          s1[outbase + m*2048 + fbase + f_hi[n] + (lk*4+r)*8 + f_lo[n]] = f2bf(-acc[m][n][r]);
  }
}

// ---------------------------------------------------------------------------
// K5: fused momentum + decay scans, 2 elems/thread, unroll 4.
// Element addresses are in fragment layout; scan is pointwise so only the
// MW1/MW2 init reads need the inverse map.
// ---------------------------------------------------------------------------
__global__ __launch_bounds__(256) void k_scan(const float* __restrict__ momv,
    const float* __restrict__ dgv, const float* __restrict__ MW1,
    const float* __restrict__ MW2, u16* __restrict__ s1w, u16* __restrict__ s2w)
{
  int bhi = blockIdx.x >> 5, eb = blockIdx.x & 31;
  int e0 = eb*512 + threadIdx.x*2;
  // decode fragment address -> (col, k); e0 even so e0+1 has k+1, same col
  int colD = ((e0>>11)<<4) + ((e0>>3)&15);
  int kD   = ((e0>>9)&3)*32 + ((e0>>7)&3)*8 + (e0&7);
  float u1a = MW1[kD*128 + colD];
  float u1b = MW1[(kD+1)*128 + colD];
  float u2a = MW2[kD*128 + colD];
  float u2b = MW2[(kD+1)*128 + colD];
  float m1a = 0.f, m1b = 0.f, m2a = 0.f, m2b = 0.f;
  size_t base = (size_t)bhi*64*16384 + e0;
  const float* mv = momv + bhi*64;
  const float* dv = dgv + bhi*64;
  #pragma unroll 4
  for (int t=0; t<64; t++){
    float g  = mv[t];
    float dg = dv[t];
    size_t idx = base + (size_t)t*16384;
    u32 a = *(const u32*)(s1w + idx);
    u32 c = *(const u32*)(s2w + idx);
    *(u32*)(s1w + idx) = (u32)f2bf(u1a) | ((u32)f2bf(u1b)<<16);
    *(u32*)(s2w + idx) = (u32)f2bf(u2a) | ((u32)f2bf(u2b)<<16);
    m1a = g*m1a + bf2f((u16)(a&0xffffu));
    m1b = g*m1b + bf2f((u16)(a>>16));
    m2a = g*m2a + bf2f((u16)(c&0xffffu));
    m2b = g*m2b + bf2f((u16)(c>>16));
    u1a = dg*u1a + m1a;
    u1b = dg*u1b + m1b;
    u2a = dg*u2a + m2a;
    u2b = dg*u2b + m2b;
  }
}

// ---------------------------------------------------------------------------
// K6: retrieval. q staged via LDS (stride 136); w1c/w2c read as coalesced
// fragment-order loads (wv*2048 + k0*512 + lane*8).
// ---------------------------------------------------------------------------
__global__ __launch_bounds__(512) void k_retr(const u16* __restrict__ qin,
    const u16* __restrict__ w1c, const u16* __restrict__ w2c,
    const float* __restrict__ gate, const float* __restrict__ gamma,
    u16* __restrict__ outp)
{
  __shared__ u16 bufQ[64*136];
  __shared__ u16 bufA[64*132];
  __shared__ float rsum[8][64];
  const int blk = blockIdx.x;
  const int bhi = blk >> 6, ci = blk & 63;
  const int b = bhi >> 2, hd = bhi & 3;
  const int tid = threadIdx.x;
  const int wv = tid>>6, lane = tid&63, lrow = lane&15, lk = lane>>4;
  const int colw = wv*16 + lrow;
  const size_t rowbase = (size_t)b*4096 + (size_t)ci*64;
  const u16* w1 = w1c + (size_t)blk*16384;
  const u16* w2 = w2c + (size_t)blk*16384;
  const int lane8 = lane*8;

  // stage q tile (64 x 128) -> LDS, coalesced
  #pragma unroll
  for (int rep=0;rep<2;rep++){
    int lin = rep*4096 + tid*8;
    int i = lin>>7, d = lin&127;
    *(uint4*)&bufQ[i*136 + d] = *(const uint4*)(qin + (rowbase+i)*512 + hd*128 + d);
  }
  __syncthreads();

  // mm1: Hq = q @ w1 ; A = silu
  {
    s16x8 wf[4];
    #pragma unroll
    for (int k0=0;k0<4;k0++) wf[k0] = *(const s16x8*)(w1 + wv*2048 + k0*512 + lane8);
    f32x4 acc[4] = {};
    #pragma unroll
    for (int k0=0;k0<4;k0++){
      #pragma unroll
      for (int m=0;m<4;m++){
        s16x8 a = *(const s16x8*)&bufQ[(m*16+lrow)*136 + k0*32 + lk*8];
        acc[m] = MFMA16(a, wf[k0], acc[m]);
      }
    }
    #pragma unroll
    for (int m=0;m<4;m++){
      #pragma unroll
      for (int r=0;r<4;r++){
        float h = acc[m][r];
        bufA[(m*16+lk*4+r)*132 + colw] = f2bf(h*sigm(h));
      }
    }
  }
  __syncthreads();

  // mm2: P = A @ w2
  f32x4 acc[4] = {};
  {
    s16x8 wf[4];
    #pragma unroll
    for (int k0=0;k0<4;k0++) wf[k0] = *(const s16x8*)(w2 + wv*2048 + k0*512 + lane8);
    #pragma unroll
    for (int k0=0;k0<4;k0++){
      #pragma unroll
      for (int m=0;m<4;m++){
        s16x8 a = *(const s16x8*)&bufA[(m*16+lrow)*132 + k0*32 + lk*8];
        acc[m] = MFMA16(a, wf[k0], acc[m]);
      }
    }
  }
  #pragma unroll
  for (int m=0;m<4;m++){
    #pragma unroll
    for (int r=0;r<4;r++){
      float p = acc[m][r]*acc[m][r];
      p += __shfl_xor(p, 1, 64);
      p += __shfl_xor(p, 2, 64);
      p += __shfl_xor(p, 4, 64);
      p += __shfl_xor(p, 8, 64);
      if (lrow == 0) rsum[wv][m*16 + lk*4 + r] = p;
    }
  }
  __syncthreads();
  float gm = gamma[hd*128 + colw] + 1.0f;
  #pragma unroll
  for (int m=0;m<4;m++){
    #pragma unroll
    for (int r=0;r<4;r++){
      int row = m*16 + lk*4 + r;
      float sum = rsum[0][row]+rsum[1][row]+rsum[2][row]+rsum[3][row]
                + rsum[4][row]+rsum[5][row]+rsum[6][row]+rsum[7][row];
      float inv = rsqrtf(sum*(1.0f/128.0f) + 1e-6f);
      float gt = gate[(rowbase+row)*4 + hd];
      outp[(rowbase+row)*512 + hd*128 + colw] = f2bf(acc[m][r]*inv*gm*gt);
    }
  }
}

// ---------------------------------------------------------------------------
extern "C" void kernel_launch(void* const* d_in, const int* in_sizes, int n_in,
                              void* d_out, int out_size, void* d_ws, size_t ws_size,
                              hipStream_t stream)
{
  const float* seq    = (const float*)d_in[0];
  const float* gstore = (const float*)d_in[1];
  const float* gret   = (const float*)d_in[2];
  const float* W_q    = (const float*)d_in[3];
  const float* W_kv   = (const float*)d_in[4];
  const float* W_step = (const float*)d_in[5];
  const float* W_mom  = (const float*)d_in[6];
  const float* W_dec  = (const float*)d_in[7];
  const float* W_gate = (const float*)d_in[8];
  const float* gamma  = (const float*)d_in[9];
  const float* W_o    = (const float*)d_in[10];
  const float* MW1    = (const float*)d_in[11];
  const float* MW2    = (const float*)d_in[12];
  float* out = (float*)d_out;

  const size_t NS = (size_t)16384*512;
  const size_t NG = (size_t)16*64*16384;
  size_t need = (5*NS + 2*NG + 524288 + 262144 + 262144 + 3*16384)*2
              + (2*65536 + 2048)*4;
  if (ws_size < need) return;

  char* ws = (char*)d_ws;
  u16* s_bf = (u16*)ws; ws += NS*2;        // s; reused as outp
  u16* r_bf = (u16*)ws; ws += NS*2;
  u16* kv_bf= (u16*)ws; ws += 2*NS*2;
  u16* q_bf = (u16*)ws; ws += NS*2;
  u16* s1   = (u16*)ws; ws += NG*2;        // -> w1c after k_scan
  u16* s2   = (u16*)ws; ws += NG*2;        // -> w2c
  u16* Wkvt = (u16*)ws; ws += (size_t)524288*2;
  u16* Wqt  = (u16*)ws; ws += (size_t)262144*2;
  u16* Wot  = (u16*)ws; ws += (size_t)262144*2;
  u16* W1tb = (u16*)ws; ws += (size_t)16384*2;
  u16* W2tb = (u16*)ws; ws += (size_t)16384*2;
  u16* W2sb = (u16*)ws; ws += (size_t)16384*2;
  float* lr   = (float*)ws; ws += (size_t)65536*4;
  float* gatep= (float*)ws; ws += (size_t)65536*4;
  float* momv = (float*)ws; ws += 1024*4;
  float* dgv  = (float*)ws; ws += 1024*4;
  u16* outp = s_bf;

  k_front<<<528, 512, 0, stream>>>(seq, gstore, gret, W_step, W_gate, W_dec, W_mom,
                                   W_kv, W_q, W_o, MW1, MW2,
                                   s_bf, r_bf, lr, gatep, momv, dgv,
                                   Wkvt, Wqt, Wot, W1tb, W2tb, W2sb);
  k_gemmAB<<<1536, 256, 0, stream>>>(s_bf, Wkvt, kv_bf, r_bf, Wqt, q_bf);
  k_grad<<<1024, 256, 0, stream>>>(kv_bf, lr, W1tb, W2tb, W2sb, s1, s2);
  k_scan<<<512, 256, 0, stream>>>(momv, dgv, MW1, MW2, s1, s2);
  k_retr<<<1024, 512, 0, stream>>>(q_bf, s1, s2, gatep, gamma, outp);
  k_gemm1<false><<<512, 256, 0, stream>>>(outp, Wot, out, 512, 512, 4, 64);
}